// Round 1
// baseline (2900.753 us; speedup 1.0000x reference)
//
#include <hip/hip_runtime.h>
#include <cstdint>
#include <math.h>

#define B 8
#define L 2048
#define D 256
#define H 128
#define NEG_INF (-INFINITY)

// ---------------------------------------------------------------------------
// Normalize bool masks (unknown layout: 1-byte bool vs int32) to int32 in ws.
// Detection: if stored as int32, every 4-byte word is 0 or 1. If stored as
// bytes, words are packed 4 bools -> with random masks some word > 1 w.p. ~1.
// ---------------------------------------------------------------------------
__global__ void mask_norm_kernel(const void* __restrict__ raw0,
                                 const void* __restrict__ raw1,
                                 int* __restrict__ out0,
                                 int* __restrict__ out1) {
    const void* raw = (blockIdx.x == 0) ? raw0 : raw1;
    int* out = (blockIdx.x == 0) ? out0 : out1;
    __shared__ int flag;
    const int t = threadIdx.x;
    if (t == 0) flag = 0;
    __syncthreads();
    const uint32_t* w = (const uint32_t*)raw;
    int local = 0;
    for (int i = t; i < (B * L) / 4; i += 256)
        if (w[i] > 1u) local = 1;
    if (local) flag = 1;
    __syncthreads();
    if (flag) {  // byte-bool layout
        const uint8_t* by = (const uint8_t*)raw;
        for (int i = t; i < B * L; i += 256) out[i] = by[i] ? 1 : 0;
    } else {     // int32 layout
        for (int i = t; i < B * L; i += 256) out[i] = w[i] ? 1 : 0;
    }
}

// ---------------------------------------------------------------------------
// Projections: pq = relu(queries @ Wq^T)  [B,L,H]
//              pk = relu(keys   @ Wk^T) * scaling
// One thread per output element; float4 loads over D.
// ---------------------------------------------------------------------------
__global__ void proj_kernel(const float* __restrict__ queries,
                            const float* __restrict__ keys,
                            const float* __restrict__ Wq,
                            const float* __restrict__ Wk,
                            const float* __restrict__ scaling,
                            float* __restrict__ pq,
                            float* __restrict__ pk) {
    const int z = blockIdx.y;  // 0 -> pq, 1 -> pk
    const int idx = blockIdx.x * 256 + threadIdx.x;  // 0 .. B*L*H-1
    const int row = idx >> 7;   // B*L row
    const int h = idx & 127;
    const float4* in4 = (const float4*)(z ? keys : queries) + (size_t)row * (D / 4);
    const float4* w4 = (const float4*)(z ? Wk : Wq) + (size_t)h * (D / 4);
    float s = 0.f;
#pragma unroll 8
    for (int i = 0; i < D / 4; ++i) {
        float4 a = in4[i];
        float4 b = w4[i];
        s += a.x * b.x + a.y * b.y + a.z * b.z + a.w * b.w;
    }
    s = fmaxf(s, 0.f);
    if (z) s *= scaling[h];
    (z ? pk : pq)[idx] = s;
}

// ---------------------------------------------------------------------------
// Flash attention over precomputed projections.
//   blockIdx.z == 0: Q=pq, K=pk, mask=m1 (over k), V=values_1 -> out[0:BLD)
//   blockIdx.z == 1: Q=pk, K=pq, mask=m2 (over q), V=values_2 -> out[BLD:2BLD)
// 32 query rows per block, 32-wide key tiles, 256 threads.
// ---------------------------------------------------------------------------
__launch_bounds__(256)
__global__ void flash_kernel(const float* __restrict__ pq,
                             const float* __restrict__ pk,
                             const int* __restrict__ m1,
                             const int* __restrict__ m2,
                             const float* __restrict__ v1,
                             const float* __restrict__ v2,
                             float* __restrict__ out) {
    const int t = threadIdx.x;
    const int bb = blockIdx.y;
    const int q0 = blockIdx.x * 32;

    const float *Q, *K, *V;
    const int* M;
    float* O;
    if (blockIdx.z == 0) { Q = pq; K = pk; M = m1; V = v1; O = out; }
    else                 { Q = pk; K = pq; M = m2; V = v2; O = out + (size_t)B * L * D; }

    __shared__ float4 q4s[32][H / 4];        // 16 KB, broadcast reads
    __shared__ float4 k4s[32][33];           // 16.9 KB, pad to break conflicts
    __shared__ __attribute__((aligned(16))) float Pt[32][36];  // P transposed [j][r]
    __shared__ float mrow[32], lrow[32], arow[32];
    __shared__ int kmask[32];

    // stage Q tile (once per block)
    {
        const float4* Q4 = (const float4*)Q + ((size_t)bb * L + q0) * (H / 4);
#pragma unroll
        for (int i = 0; i < 4; ++i) {
            int idx = t + 256 * i;          // 0..1023
            int r = idx >> 5, c = idx & 31;
            q4s[r][c] = Q4[(size_t)r * (H / 4) + c];
        }
    }
    if (t < 32) { mrow[t] = NEG_INF; lrow[t] = 0.f; }

    float acc[8][4];
#pragma unroll
    for (int i = 0; i < 8; ++i)
#pragma unroll
        for (int c = 0; c < 4; ++c) acc[i][c] = 0.f;

    const int dgrp = t & 63;   // float4 column group (d = dgrp*4)
    const int rgrp = t >> 6;   // row group (rows rgrp*8 .. rgrp*8+7)

    for (int kt = 0; kt < L / 32; ++kt) {
        const int k0 = kt * 32;
        // stage K tile + mask
        {
            const float4* K4 = (const float4*)K + ((size_t)bb * L + k0) * (H / 4);
#pragma unroll
            for (int i = 0; i < 4; ++i) {
                int idx = t + 256 * i;
                int r = idx >> 5, c = idx & 31;
                k4s[r][c] = K4[(size_t)r * (H / 4) + c];
            }
            if (t < 32) kmask[t] = M[(size_t)bb * L + k0 + t];
        }
        __syncthreads();

        // scores: S[r][j] = q_r . k_j ; thread t -> col j=t&31, rows (t>>5)*4 ..+3
        {
            const int j = t & 31;
            const int r0 = (t >> 5) * 4;
            float s0 = 0.f, s1 = 0.f, s2 = 0.f, s3 = 0.f;
#pragma unroll 8
            for (int h4 = 0; h4 < H / 4; ++h4) {
                float4 kk = k4s[j][h4];
                float4 q;
                q = q4s[r0 + 0][h4]; s0 += q.x * kk.x + q.y * kk.y + q.z * kk.z + q.w * kk.w;
                q = q4s[r0 + 1][h4]; s1 += q.x * kk.x + q.y * kk.y + q.z * kk.z + q.w * kk.w;
                q = q4s[r0 + 2][h4]; s2 += q.x * kk.x + q.y * kk.y + q.z * kk.z + q.w * kk.w;
                q = q4s[r0 + 3][h4]; s3 += q.x * kk.x + q.y * kk.y + q.z * kk.z + q.w * kk.w;
            }
            const bool masked = (kmask[j] != 0);
            Pt[j][r0 + 0] = masked ? NEG_INF : s0;
            Pt[j][r0 + 1] = masked ? NEG_INF : s1;
            Pt[j][r0 + 2] = masked ? NEG_INF : s2;
            Pt[j][r0 + 3] = masked ? NEG_INF : s3;
        }
        __syncthreads();

        // online softmax: row r handled by 8 threads (g = t&7), 4 cols each
        {
            const int r = t >> 3;
            const int g = t & 7;
            float sv[4];
            float tmax = NEG_INF;
#pragma unroll
            for (int i = 0; i < 4; ++i) {
                sv[i] = Pt[g * 4 + i][r];
                tmax = fmaxf(tmax, sv[i]);
            }
#pragma unroll
            for (int off = 1; off < 8; off <<= 1)
                tmax = fmaxf(tmax, __shfl_xor(tmax, off));
            const float m_old = mrow[r];
            const float m_new = fmaxf(m_old, tmax);
            float a;
            float psum = 0.f;
            if (m_new == NEG_INF) {  // everything so far masked
                a = 1.f;
#pragma unroll
                for (int i = 0; i < 4; ++i) Pt[g * 4 + i][r] = 0.f;
            } else {
                a = __expf(m_old - m_new);  // m_old=-inf -> 0
#pragma unroll
                for (int i = 0; i < 4; ++i) {
                    float p = __expf(sv[i] - m_new);  // sv=-inf -> 0
                    Pt[g * 4 + i][r] = p;
                    psum += p;
                }
            }
#pragma unroll
            for (int off = 1; off < 8; off <<= 1)
                psum += __shfl_xor(psum, off);
            if (g == 0) {
                arow[r] = a;
                mrow[r] = m_new;
                lrow[r] = lrow[r] * a + psum;
            }
        }
        __syncthreads();

        // PV: thread owns 8 rows x 4 cols. Coalesced float4 V loads.
        {
            const float4* V4 = (const float4*)V + ((size_t)bb * L + k0) * (D / 4) + dgrp;
#pragma unroll
            for (int rr = 0; rr < 8; ++rr) {
                const float a = arow[rgrp * 8 + rr];
#pragma unroll
                for (int c = 0; c < 4; ++c) acc[rr][c] *= a;
            }
            for (int j = 0; j < 32; ++j) {
                const float4 v = V4[(size_t)j * (D / 4)];
                const float4 p0 = *(const float4*)&Pt[j][rgrp * 8];
                const float4 p1 = *(const float4*)&Pt[j][rgrp * 8 + 4];
                acc[0][0] += p0.x * v.x; acc[0][1] += p0.x * v.y; acc[0][2] += p0.x * v.z; acc[0][3] += p0.x * v.w;
                acc[1][0] += p0.y * v.x; acc[1][1] += p0.y * v.y; acc[1][2] += p0.y * v.z; acc[1][3] += p0.y * v.w;
                acc[2][0] += p0.z * v.x; acc[2][1] += p0.z * v.y; acc[2][2] += p0.z * v.z; acc[2][3] += p0.z * v.w;
                acc[3][0] += p0.w * v.x; acc[3][1] += p0.w * v.y; acc[3][2] += p0.w * v.z; acc[3][3] += p0.w * v.w;
                acc[4][0] += p1.x * v.x; acc[4][1] += p1.x * v.y; acc[4][2] += p1.x * v.z; acc[4][3] += p1.x * v.w;
                acc[5][0] += p1.y * v.x; acc[5][1] += p1.y * v.y; acc[5][2] += p1.y * v.z; acc[5][3] += p1.y * v.w;
                acc[6][0] += p1.z * v.x; acc[6][1] += p1.z * v.y; acc[6][2] += p1.z * v.z; acc[6][3] += p1.z * v.w;
                acc[7][0] += p1.w * v.x; acc[7][1] += p1.w * v.y; acc[7][2] += p1.w * v.z; acc[7][3] += p1.w * v.w;
            }
        }
        // no extra sync needed: next-iter staging touches only k4s/kmask,
        // which PV never reads; the loop-top __syncthreads orders Pt reuse.
    }

    // epilogue: O[b][q0+r][:] = acc / l
    {
        float4* O4 = (float4*)O + ((size_t)bb * L + q0) * (D / 4) + dgrp;
#pragma unroll
        for (int rr = 0; rr < 8; ++rr) {
            const int r = rgrp * 8 + rr;
            const float lr = lrow[r];
            const float inv = (lr > 0.f) ? (1.f / lr) : 0.f;
            float4 o;
            o.x = acc[rr][0] * inv;
            o.y = acc[rr][1] * inv;
            o.z = acc[rr][2] * inv;
            o.w = acc[rr][3] * inv;
            O4[(size_t)r * (D / 4)] = o;
        }
    }
}

extern "C" void kernel_launch(void* const* d_in, const int* in_sizes, int n_in,
                              void* d_out, int out_size, void* d_ws, size_t ws_size,
                              hipStream_t stream) {
    const float* queries  = (const float*)d_in[0];
    const float* keys     = (const float*)d_in[1];
    const float* values_1 = (const float*)d_in[2];
    const void*  v1_mask  = d_in[3];
    const float* values_2 = (const float*)d_in[4];
    const void*  v2_mask  = d_in[5];
    const float* Wq       = (const float*)d_in[6];
    const float* Wk       = (const float*)d_in[7];
    const float* scaling  = (const float*)d_in[8];
    float* out = (float*)d_out;

    float* pq = (float*)d_ws;                       // B*L*H floats
    float* pk = pq + (size_t)B * L * H;             // B*L*H floats
    int* m1 = (int*)(pk + (size_t)B * L * H);       // B*L ints
    int* m2 = m1 + B * L;                           // B*L ints

    mask_norm_kernel<<<2, 256, 0, stream>>>(v1_mask, v2_mask, m1, m2);
    proj_kernel<<<dim3(B * L * H / 256, 2), 256, 0, stream>>>(
        queries, keys, Wq, Wk, scaling, pq, pk);
    flash_kernel<<<dim3(L / 32, B, 2), 256, 0, stream>>>(
        pq, pk, m1, m2, values_1, values_2, out);
}

// Round 3
// 863.359 us; speedup vs baseline: 3.3598x; 3.3598x over previous
//
#include <hip/hip_runtime.h>
#include <cstdint>
#include <math.h>

#define B 8
#define L 2048
#define D 256
#define H 128

typedef __attribute__((ext_vector_type(8))) short bf16x8;
typedef __attribute__((ext_vector_type(4))) float f32x4;
typedef unsigned short ushort;
typedef unsigned int uint;

__device__ __forceinline__ ushort f2bf(float x) {
    uint u = __float_as_uint(x);
    uint r = (u + 0x7fffu + ((u >> 16) & 1u)) >> 16;
    return (ushort)r;
}
__device__ __forceinline__ float bf2f(ushort h) {
    return __uint_as_float((uint)h << 16);
}

// ---------------------------------------------------------------------------
// Masks -> float bias arrays (0.0 where keep, -inf where masked).
// Auto-detect byte-bool vs int32 layout (random masks make words >1 iff bytes).
// ---------------------------------------------------------------------------
__global__ void mask_bias_kernel(const void* __restrict__ raw0,
                                 const void* __restrict__ raw1,
                                 float* __restrict__ out0,
                                 float* __restrict__ out1) {
    const void* raw = (blockIdx.x == 0) ? raw0 : raw1;
    float* out = (blockIdx.x == 0) ? out0 : out1;
    __shared__ int flag;
    const int t = threadIdx.x;
    if (t == 0) flag = 0;
    __syncthreads();
    const uint* w = (const uint*)raw;
    int local = 0;
    for (int i = t; i < (B * L) / 4; i += 256)
        if (w[i] > 1u) local = 1;
    if (local) flag = 1;
    __syncthreads();
    if (flag) {  // byte-bool layout
        const uint8_t* by = (const uint8_t*)raw;
        for (int i = t; i < B * L; i += 256) out[i] = by[i] ? -INFINITY : 0.f;
    } else {     // int32 layout
        for (int i = t; i < B * L; i += 256) out[i] = w[i] ? -INFINITY : 0.f;
    }
}

// ---------------------------------------------------------------------------
// Projections -> split bf16 (hi + lo): pq = relu(q @ Wq^T),
// pk = relu(k @ Wk^T) * scaling.  lo = bf16(x - float(hi)).
// ---------------------------------------------------------------------------
__global__ void proj_kernel(const float* __restrict__ queries,
                            const float* __restrict__ keys,
                            const float* __restrict__ Wq,
                            const float* __restrict__ Wk,
                            const float* __restrict__ scaling,
                            ushort* __restrict__ pq_hi,
                            ushort* __restrict__ pq_lo,
                            ushort* __restrict__ pk_hi,
                            ushort* __restrict__ pk_lo) {
    const int z = blockIdx.y;  // 0 -> pq, 1 -> pk
    const int idx = blockIdx.x * 256 + threadIdx.x;  // 0 .. B*L*H/4-1
    const int h = idx & 127;
    const int r0 = (idx >> 7) * 4;
    const float4* in4 = (const float4*)(z ? keys : queries) + (size_t)r0 * (D / 4);
    const float4* w4 = (const float4*)(z ? Wk : Wq) + (size_t)h * (D / 4);
    float s0 = 0.f, s1 = 0.f, s2 = 0.f, s3 = 0.f;
#pragma unroll 4
    for (int i = 0; i < D / 4; ++i) {
        float4 wv = w4[i];
        float4 a0 = in4[i];
        float4 a1 = in4[i + 64];
        float4 a2 = in4[i + 128];
        float4 a3 = in4[i + 192];
        s0 += a0.x * wv.x + a0.y * wv.y + a0.z * wv.z + a0.w * wv.w;
        s1 += a1.x * wv.x + a1.y * wv.y + a1.z * wv.z + a1.w * wv.w;
        s2 += a2.x * wv.x + a2.y * wv.y + a2.z * wv.z + a2.w * wv.w;
        s3 += a3.x * wv.x + a3.y * wv.y + a3.z * wv.z + a3.w * wv.w;
    }
    s0 = fmaxf(s0, 0.f); s1 = fmaxf(s1, 0.f); s2 = fmaxf(s2, 0.f); s3 = fmaxf(s3, 0.f);
    if (z) {
        const float sc = scaling[h];
        s0 *= sc; s1 *= sc; s2 *= sc; s3 *= sc;
    }
    ushort* ohi = (z ? pk_hi : pq_hi) + (size_t)r0 * H + h;
    ushort* olo = (z ? pk_lo : pq_lo) + (size_t)r0 * H + h;
    float v[4] = {s0, s1, s2, s3};
#pragma unroll
    for (int r = 0; r < 4; ++r) {
        ushort hi = f2bf(v[r]);
        ohi[r * H] = hi;
        olo[r * H] = f2bf(v[r] - bf2f(hi));
    }
}

// ---------------------------------------------------------------------------
// V transpose + bf16: Vt[b][d][key] from V[b][key][d], for both value tensors.
// ---------------------------------------------------------------------------
__global__ void vtrans_kernel(const float* __restrict__ v1,
                              const float* __restrict__ v2,
                              ushort* __restrict__ vt1,
                              ushort* __restrict__ vt2) {
    const int t = threadIdx.x;
    const int zz = blockIdx.z;        // 0..15
    const int b = zz & 7;
    const int which = zz >> 3;
    const float* src = (which ? v2 : v1) + (size_t)b * L * D;
    ushort* dst = (which ? vt2 : vt1) + (size_t)b * D * L;
    const int k0 = blockIdx.x * 64;
    const int d0 = blockIdx.y * 64;
    __shared__ float lt[64][65];
#pragma unroll
    for (int p = 0; p < 4; ++p) {
        int kr = p * 16 + (t >> 4);
        float4 v = *(const float4*)(src + (size_t)(k0 + kr) * D + d0 + (t & 15) * 4);
        lt[(t & 15) * 4 + 0][kr] = v.x;
        lt[(t & 15) * 4 + 1][kr] = v.y;
        lt[(t & 15) * 4 + 2][kr] = v.z;
        lt[(t & 15) * 4 + 3][kr] = v.w;
    }
    __syncthreads();
#pragma unroll
    for (int p = 0; p < 4; ++p) {
        int d = p * 16 + (t >> 4);
        int c = t & 15;
        uint* orow = (uint*)(dst + (size_t)(d0 + d) * L + k0);
        float a0 = lt[d][c * 2], a1 = lt[d][c * 2 + 1];
        float b0 = lt[d][32 + c * 2], b1 = lt[d][32 + c * 2 + 1];
        orow[c] = (uint)f2bf(a0) | ((uint)f2bf(a1) << 16);
        orow[c + 16] = (uint)f2bf(b0) | ((uint)f2bf(b1) << 16);
    }
}

// ---------------------------------------------------------------------------
// MFMA flash attention, split-precision QK^T (hi*hi + lo*hi + hi*lo).
// Block = 64 q-rows (4 waves x 16), k-tiles of 64. Q-frags in registers for
// the whole K-loop; K/V frags straight from L2/L3; P transposed through a
// per-wave LDS buffer (no __syncthreads in K-loop).
//   z=0: Q=pq, K=pk, bias=fb1 (over keys), V=Vt1 -> out[0:BLD)
//   z=1: Q=pk, K=pq, bias=fb2,              V=Vt2 -> out[BLD:2BLD)
// ---------------------------------------------------------------------------
__launch_bounds__(256, 2)
__global__ void flash_mfma_kernel(const ushort* __restrict__ pq_hi,
                                  const ushort* __restrict__ pq_lo,
                                  const ushort* __restrict__ pk_hi,
                                  const ushort* __restrict__ pk_lo,
                                  const float* __restrict__ fb1,
                                  const float* __restrict__ fb2,
                                  const ushort* __restrict__ vt1,
                                  const ushort* __restrict__ vt2,
                                  float* __restrict__ out) {
    const int t = threadIdx.x;
    const int w = t >> 6;          // wave 0..3
    const int lane = t & 63;
    const int l15 = lane & 15;
    const int quad = lane >> 4;
    const int bb = blockIdx.y;
    const int q0 = blockIdx.x * 64 + w * 16;

    const ushort *Qh, *Ql, *Kh, *Kl, *Vt;
    const float* fb;
    float* O;
    if (blockIdx.z == 0) { Qh = pq_hi; Ql = pq_lo; Kh = pk_hi; Kl = pk_lo; fb = fb1; Vt = vt1; O = out; }
    else                 { Qh = pk_hi; Ql = pk_lo; Kh = pq_hi; Kl = pq_lo; fb = fb2; Vt = vt2; O = out + (size_t)B * L * D; }

    // per-wave P buffer: 16 rows x 64 keys bf16, pad to 88 (176B stride, 16B-aligned)
    __shared__ ushort Plds[4][16][88];
    ushort (*Pw)[88] = Plds[w];

    const size_t bL = (size_t)bb * L;

    // A-frags (Q hi/lo): A[m=l15][k=quad*8+j], 4 h-blocks of K=32
    bf16x8 aqh[4], aql[4];
    {
        const ushort* qh = Qh + (bL + q0 + l15) * H + quad * 8;
        const ushort* ql = Ql + (bL + q0 + l15) * H + quad * 8;
#pragma unroll
        for (int hb = 0; hb < 4; ++hb) {
            aqh[hb] = *(const bf16x8*)(qh + hb * 32);
            aql[hb] = *(const bf16x8*)(ql + hb * 32);
        }
    }

    f32x4 acc[16];
#pragma unroll
    for (int ct = 0; ct < 16; ++ct) acc[ct] = (f32x4){0.f, 0.f, 0.f, 0.f};
    float m_run[4], l_run[4];
#pragma unroll
    for (int r = 0; r < 4; ++r) { m_run[r] = -INFINITY; l_run[r] = 0.f; }

    const float* fbb = fb + bL;
    const ushort* Vbase = Vt + (size_t)bb * D * L;  // [d][key]

    for (int k0 = 0; k0 < L; k0 += 64) {
        // mask bias for the 4 key sub-tiles (col = jt*16 + l15)
        float bias[4];
#pragma unroll
        for (int jt = 0; jt < 4; ++jt) bias[jt] = fbb[k0 + jt * 16 + l15];

        // QK^T split precision: S = Qhi*Khi + Qlo*Khi + Qhi*Klo
        f32x4 s[4];
#pragma unroll
        for (int jt = 0; jt < 4; ++jt) {
            const ushort* krh = Kh + (bL + k0 + jt * 16 + l15) * H + quad * 8;
            const ushort* krl = Kl + (bL + k0 + jt * 16 + l15) * H + quad * 8;
            f32x4 sv = (f32x4){0.f, 0.f, 0.f, 0.f};
#pragma unroll
            for (int hb = 0; hb < 4; ++hb) {
                bf16x8 bkh = *(const bf16x8*)(krh + hb * 32);
                bf16x8 bkl = *(const bf16x8*)(krl + hb * 32);
                sv = __builtin_amdgcn_mfma_f32_16x16x32_bf16(aqh[hb], bkh, sv, 0, 0, 0);
                sv = __builtin_amdgcn_mfma_f32_16x16x32_bf16(aql[hb], bkh, sv, 0, 0, 0);
                sv = __builtin_amdgcn_mfma_f32_16x16x32_bf16(aqh[hb], bkl, sv, 0, 0, 0);
            }
            s[jt] = sv;
        }

        // apply mask bias
#pragma unroll
        for (int jt = 0; jt < 4; ++jt)
#pragma unroll
            for (int r = 0; r < 4; ++r) s[jt][r] += bias[jt];

        // online softmax per row (row = quad*4 + r, 16 lanes per row).
        // P is rounded to bf16 BEFORE the denominator sum so numerator
        // (bf16 PV MFMA) and denominator use identical weights.
        float al[4];
#pragma unroll
        for (int r = 0; r < 4; ++r) {
            float tm = fmaxf(fmaxf(s[0][r], s[1][r]), fmaxf(s[2][r], s[3][r]));
            tm = fmaxf(tm, __shfl_xor(tm, 1));
            tm = fmaxf(tm, __shfl_xor(tm, 2));
            tm = fmaxf(tm, __shfl_xor(tm, 4));
            tm = fmaxf(tm, __shfl_xor(tm, 8));
            const float mn = fmaxf(m_run[r], tm);
            const float alpha = (m_run[r] == -INFINITY) ? 0.f : __expf(m_run[r] - mn);
            const float safe = (mn == -INFINITY) ? 0.f : mn;
            float ps = 0.f;
#pragma unroll
            for (int jt = 0; jt < 4; ++jt) {
                ushort pb = f2bf(__expf(s[jt][r] - safe));
                Pw[quad * 4 + r][jt * 16 + l15] = pb;
                ps += bf2f(pb);
            }
            ps += __shfl_xor(ps, 1);
            ps += __shfl_xor(ps, 2);
            ps += __shfl_xor(ps, 4);
            ps += __shfl_xor(ps, 8);
            m_run[r] = mn;
            l_run[r] = l_run[r] * alpha + ps;
            al[r] = alpha;
        }

        // rescale accumulator
#pragma unroll
        for (int ct = 0; ct < 16; ++ct)
#pragma unroll
            for (int r = 0; r < 4; ++r) acc[ct][r] *= al[r];

        // PV: O += P(16x64) x V(64x256); A from LDS, B straight from Vt
#pragma unroll
        for (int kk = 0; kk < 2; ++kk) {
            bf16x8 pa = *(const bf16x8*)&Pw[l15][kk * 32 + quad * 8];
            const ushort* vcol = Vbase + k0 + kk * 32 + quad * 8 + (size_t)l15 * L;
#pragma unroll
            for (int ct = 0; ct < 16; ++ct) {
                bf16x8 bv = *(const bf16x8*)(vcol + (size_t)ct * 16 * L);
                acc[ct] = __builtin_amdgcn_mfma_f32_16x16x32_bf16(pa, bv, acc[ct], 0, 0, 0);
            }
        }
    }

    // epilogue: divide by l, store
    float inv[4];
#pragma unroll
    for (int r = 0; r < 4; ++r)
        inv[r] = (l_run[r] > 0.f) ? (1.f / l_run[r]) : 0.f;
#pragma unroll
    for (int r = 0; r < 4; ++r) {
        float* orow = O + (bL + q0 + quad * 4 + r) * (size_t)D + l15;
#pragma unroll
        for (int ct = 0; ct < 16; ++ct)
            orow[ct * 16] = acc[ct][r] * inv[r];
    }
}

extern "C" void kernel_launch(void* const* d_in, const int* in_sizes, int n_in,
                              void* d_out, int out_size, void* d_ws, size_t ws_size,
                              hipStream_t stream) {
    const float* queries  = (const float*)d_in[0];
    const float* keys     = (const float*)d_in[1];
    const float* values_1 = (const float*)d_in[2];
    const void*  v1_mask  = d_in[3];
    const float* values_2 = (const float*)d_in[4];
    const void*  v2_mask  = d_in[5];
    const float* Wq       = (const float*)d_in[6];
    const float* Wk       = (const float*)d_in[7];
    const float* scaling  = (const float*)d_in[8];
    float* out = (float*)d_out;

    ushort* pq_hi = (ushort*)d_ws;                    // B*L*H bf16 (4 MB each)
    ushort* pq_lo = pq_hi + (size_t)B * L * H;
    ushort* pk_hi = pq_lo + (size_t)B * L * H;
    ushort* pk_lo = pk_hi + (size_t)B * L * H;
    ushort* vt1   = pk_lo + (size_t)B * L * H;        // B*D*L bf16 (8 MB each)
    ushort* vt2   = vt1 + (size_t)B * L * D;
    float* fb1 = (float*)(vt2 + (size_t)B * L * D);   // 64 KB each
    float* fb2 = fb1 + B * L;

    mask_bias_kernel<<<2, 256, 0, stream>>>(v1_mask, v2_mask, fb1, fb2);
    proj_kernel<<<dim3(B * L * H / 4 / 256, 2), 256, 0, stream>>>(
        queries, keys, Wq, Wk, scaling, pq_hi, pq_lo, pk_hi, pk_lo);
    vtrans_kernel<<<dim3(L / 64, D / 64, B * 2), 256, 0, stream>>>(
        values_1, values_2, vt1, vt2);
    flash_mfma_kernel<<<dim3(L / 64, B, 2), 256, 0, stream>>>(
        pq_hi, pq_lo, pk_hi, pk_lo, fb1, fb2, vt1, vt2, out);
}

// Round 4
// 747.698 us; speedup vs baseline: 3.8796x; 1.1547x over previous
//
#include <hip/hip_runtime.h>
#include <cstdint>
#include <math.h>

#define B 8
#define L 2048
#define D 256
#define H 128

typedef __attribute__((ext_vector_type(8))) short bf16x8;
typedef __attribute__((ext_vector_type(4))) float f32x4;
typedef unsigned short ushort;
typedef unsigned int uint;

// Packed fragment layouts (all wave loads = contiguous 1KB blocks):
//  P/K arrays (B*L*H):  off = ((row>>4)*4 + h/32)*512 + (row&15)*32 + ((h>>3)&3)*8 + (h&7)
//  V arrays  (B*L*D):  off = (((b*(L/64)+key/64)*2 + (key%64)/32)*16 + d/16)*512
//                            + (d&15)*32 + ((key%32)/8)*8 + (key&7)

__device__ __forceinline__ ushort f2bf(float x) {
    uint u = __float_as_uint(x);
    uint r = (u + 0x7fffu + ((u >> 16) & 1u)) >> 16;
    return (ushort)r;
}
__device__ __forceinline__ float bf2f(ushort h) {
    return __uint_as_float((uint)h << 16);
}

// ---------------------------------------------------------------------------
// Masks -> float bias arrays (0.0 keep, -inf masked). Auto-detect byte/int32.
// ---------------------------------------------------------------------------
__global__ void mask_bias_kernel(const void* __restrict__ raw0,
                                 const void* __restrict__ raw1,
                                 float* __restrict__ out0,
                                 float* __restrict__ out1) {
    const void* raw = (blockIdx.x == 0) ? raw0 : raw1;
    float* out = (blockIdx.x == 0) ? out0 : out1;
    __shared__ int flag;
    const int t = threadIdx.x;
    if (t == 0) flag = 0;
    __syncthreads();
    const uint* w = (const uint*)raw;
    int local = 0;
    for (int i = t; i < (B * L) / 4; i += 256)
        if (w[i] > 1u) local = 1;
    if (local) flag = 1;
    __syncthreads();
    if (flag) {
        const uint8_t* by = (const uint8_t*)raw;
        for (int i = t; i < B * L; i += 256) out[i] = by[i] ? -INFINITY : 0.f;
    } else {
        for (int i = t; i < B * L; i += 256) out[i] = w[i] ? -INFINITY : 0.f;
    }
}

// ---------------------------------------------------------------------------
// Projections -> split bf16 (hi+lo) in packed fragment layout.
// W half (64 h x 256 d fp32) staged in LDS with XOR swizzle; input rows are
// wave-broadcast (1 txn). Block: 16 rows x 64 h; thread: 4 rows x 1 h.
// grid = (B*L/16, 2 h-halves, 2 tensors)
// ---------------------------------------------------------------------------
__launch_bounds__(256, 2)
__global__ void proj_kernel(const float* __restrict__ queries,
                            const float* __restrict__ keys,
                            const float* __restrict__ Wq,
                            const float* __restrict__ Wk,
                            const float* __restrict__ scaling,
                            ushort* __restrict__ pq_hi,
                            ushort* __restrict__ pq_lo,
                            ushort* __restrict__ pk_hi,
                            ushort* __restrict__ pk_lo) {
    const int t = threadIdx.x;
    const int z = blockIdx.z;        // 0 -> pq, 1 -> pk
    const int h0 = blockIdx.y * 64;  // h half
    const float* in = z ? keys : queries;
    const float4* W4 = (const float4*)(z ? Wk : Wq);

    __shared__ float4 Wl[64 * 64];   // 64 KB, XOR-swizzled
#pragma unroll
    for (int j = 0; j < 16; ++j) {
        int idx = t + 256 * j;
        int h = idx >> 6, i = idx & 63;
        Wl[h * 64 + (i ^ h)] = W4[(size_t)(h0 + h) * 64 + i];
    }
    __syncthreads();

    const int hl = t & 63;
    const int h = h0 + hl;
    const int rg = t >> 6;
    const int r0 = blockIdx.x * 16 + rg * 4;   // global row (over B*L)
    const float4* a = (const float4*)in + (size_t)r0 * 64;

    float s0 = 0.f, s1 = 0.f, s2 = 0.f, s3 = 0.f;
#pragma unroll 8
    for (int i = 0; i < 64; ++i) {
        float4 wv = Wl[hl * 64 + (i ^ hl)];
        float4 x0 = a[i];
        float4 x1 = a[i + 64];
        float4 x2 = a[i + 128];
        float4 x3 = a[i + 192];
        s0 += x0.x * wv.x + x0.y * wv.y + x0.z * wv.z + x0.w * wv.w;
        s1 += x1.x * wv.x + x1.y * wv.y + x1.z * wv.z + x1.w * wv.w;
        s2 += x2.x * wv.x + x2.y * wv.y + x2.z * wv.z + x2.w * wv.w;
        s3 += x3.x * wv.x + x3.y * wv.y + x3.z * wv.z + x3.w * wv.w;
    }
    s0 = fmaxf(s0, 0.f); s1 = fmaxf(s1, 0.f); s2 = fmaxf(s2, 0.f); s3 = fmaxf(s3, 0.f);
    if (z) {
        const float sc = scaling[h];
        s0 *= sc; s1 *= sc; s2 *= sc; s3 *= sc;
    }
    ushort* ohi = z ? pk_hi : pq_hi;
    ushort* olo = z ? pk_lo : pq_lo;
    const int hb = h >> 5, hq = (h >> 3) & 3, e = h & 7;
    float v[4] = {s0, s1, s2, s3};
#pragma unroll
    for (int r = 0; r < 4; ++r) {
        int rr = r0 + r;
        size_t off = ((size_t)(rr >> 4) * 4 + hb) * 512 + (rr & 15) * 32 + hq * 8 + e;
        ushort hi = f2bf(v[r]);
        ohi[off] = hi;
        olo[off] = f2bf(v[r] - bf2f(hi));
    }
}

// ---------------------------------------------------------------------------
// V -> bf16 packed fragment layout, via LDS transpose.
// grid = (L/64, D/64, B*2); block tile = 64 keys x 64 d.
// ---------------------------------------------------------------------------
__global__ void vtrans_kernel(const float* __restrict__ v1,
                              const float* __restrict__ v2,
                              ushort* __restrict__ vt1,
                              ushort* __restrict__ vt2) {
    const int t = threadIdx.x;
    const int zz = blockIdx.z;
    const int b = zz & 7;
    const int which = zz >> 3;
    const float* src = (which ? v2 : v1) + (size_t)b * L * D;
    ushort* dst = which ? vt2 : vt1;
    const int k0 = blockIdx.x * 64;
    const int d0 = blockIdx.y * 64;
    __shared__ float lt[64][65];   // lt[d][key]
#pragma unroll
    for (int p = 0; p < 4; ++p) {
        int kr = p * 16 + (t >> 4);
        float4 v = *(const float4*)(src + (size_t)(k0 + kr) * D + d0 + (t & 15) * 4);
        lt[(t & 15) * 4 + 0][kr] = v.x;
        lt[(t & 15) * 4 + 1][kr] = v.y;
        lt[(t & 15) * 4 + 2][kr] = v.z;
        lt[(t & 15) * 4 + 3][kr] = v.w;
    }
    __syncthreads();
    const int d = t & 63;
    const int kk = (t >> 6) & 1;
    const int qp = t >> 7;                 // 0..1 -> quad pair
    const size_t bt2 = (size_t)b * (L / 64) + (k0 >> 6);
    const int ct = (d0 + d) >> 4;
    ushort* base = dst + ((bt2 * 2 + kk) * 16 + ct) * 512 + (size_t)(d & 15) * 32;
#pragma unroll
    for (int s = 0; s < 2; ++s) {
        const int qv = qp * 2 + s;
        const float* lr = &lt[d][kk * 32 + qv * 8];
        uint4 u;
        u.x = (uint)f2bf(lr[0]) | ((uint)f2bf(lr[1]) << 16);
        u.y = (uint)f2bf(lr[2]) | ((uint)f2bf(lr[3]) << 16);
        u.z = (uint)f2bf(lr[4]) | ((uint)f2bf(lr[5]) << 16);
        u.w = (uint)f2bf(lr[6]) | ((uint)f2bf(lr[7]) << 16);
        *(uint4*)(base + qv * 8) = u;
    }
}

// ---------------------------------------------------------------------------
// MFMA flash attention, split-precision QK^T, packed fragment loads.
// Block = 64 q-rows (4 waves x 16), k-tiles of 64; no __syncthreads in K-loop.
// ---------------------------------------------------------------------------
__launch_bounds__(256, 2)
__global__ void flash_mfma_kernel(const ushort* __restrict__ pq_hi,
                                  const ushort* __restrict__ pq_lo,
                                  const ushort* __restrict__ pk_hi,
                                  const ushort* __restrict__ pk_lo,
                                  const float* __restrict__ fb1,
                                  const float* __restrict__ fb2,
                                  const ushort* __restrict__ vt1,
                                  const ushort* __restrict__ vt2,
                                  float* __restrict__ out) {
    const int t = threadIdx.x;
    const int w = t >> 6;
    const int lane = t & 63;
    const int l15 = lane & 15;
    const int quad = lane >> 4;
    const int bb = blockIdx.y;
    const int q0 = blockIdx.x * 64 + w * 16;

    const ushort *Qh, *Ql, *Kh, *Kl, *Vt;
    const float* fb;
    float* O;
    if (blockIdx.z == 0) { Qh = pq_hi; Ql = pq_lo; Kh = pk_hi; Kl = pk_lo; fb = fb1; Vt = vt1; O = out; }
    else                 { Qh = pk_hi; Ql = pk_lo; Kh = pq_hi; Kl = pq_lo; fb = fb2; Vt = vt2; O = out + (size_t)B * L * D; }

    __shared__ ushort Plds[4][16][88];
    ushort (*Pw)[88] = Plds[w];

    const size_t bL = (size_t)bb * L;
    const size_t lqoff = (size_t)l15 * 32 + quad * 8;

    // A-frags (Q hi/lo): contiguous 1KB blocks per (rowtile, hb)
    bf16x8 aqh[4], aql[4];
    {
        const ushort* qh = Qh + ((size_t)((bL + q0) >> 4) * 4) * 512 + lqoff;
        const ushort* ql = Ql + ((size_t)((bL + q0) >> 4) * 4) * 512 + lqoff;
#pragma unroll
        for (int hb = 0; hb < 4; ++hb) {
            aqh[hb] = *(const bf16x8*)(qh + hb * 512);
            aql[hb] = *(const bf16x8*)(ql + hb * 512);
        }
    }

    f32x4 acc[16];
#pragma unroll
    for (int ct = 0; ct < 16; ++ct) acc[ct] = (f32x4){0.f, 0.f, 0.f, 0.f};
    float m_run[4], l_run[4];
#pragma unroll
    for (int r = 0; r < 4; ++r) { m_run[r] = -INFINITY; l_run[r] = 0.f; }

    const float* fbb = fb + bL;

    for (int k0 = 0; k0 < L; k0 += 64) {
        float bias[4];
#pragma unroll
        for (int jt = 0; jt < 4; ++jt) bias[jt] = fbb[k0 + jt * 16 + l15];

        // QK^T split precision: S = Qhi*Khi + Qlo*Khi + Qhi*Klo
        const ushort* kh0 = Kh + ((size_t)((bL + k0) >> 4)) * 2048 + lqoff;
        const ushort* kl0 = Kl + ((size_t)((bL + k0) >> 4)) * 2048 + lqoff;
        f32x4 s[4];
#pragma unroll
        for (int jt = 0; jt < 4; ++jt) {
            f32x4 sv = (f32x4){0.f, 0.f, 0.f, 0.f};
#pragma unroll
            for (int hb = 0; hb < 4; ++hb) {
                bf16x8 bkh = *(const bf16x8*)(kh0 + jt * 2048 + hb * 512);
                bf16x8 bkl = *(const bf16x8*)(kl0 + jt * 2048 + hb * 512);
                sv = __builtin_amdgcn_mfma_f32_16x16x32_bf16(aqh[hb], bkh, sv, 0, 0, 0);
                sv = __builtin_amdgcn_mfma_f32_16x16x32_bf16(aql[hb], bkh, sv, 0, 0, 0);
                sv = __builtin_amdgcn_mfma_f32_16x16x32_bf16(aqh[hb], bkl, sv, 0, 0, 0);
            }
            s[jt] = sv;
        }

#pragma unroll
        for (int jt = 0; jt < 4; ++jt)
#pragma unroll
            for (int r = 0; r < 4; ++r) s[jt][r] += bias[jt];

        // online softmax; P rounded to bf16 before denominator sum
        float al[4];
#pragma unroll
        for (int r = 0; r < 4; ++r) {
            float tm = fmaxf(fmaxf(s[0][r], s[1][r]), fmaxf(s[2][r], s[3][r]));
            tm = fmaxf(tm, __shfl_xor(tm, 1));
            tm = fmaxf(tm, __shfl_xor(tm, 2));
            tm = fmaxf(tm, __shfl_xor(tm, 4));
            tm = fmaxf(tm, __shfl_xor(tm, 8));
            const float mn = fmaxf(m_run[r], tm);
            const float alpha = (m_run[r] == -INFINITY) ? 0.f : __expf(m_run[r] - mn);
            const float safe = (mn == -INFINITY) ? 0.f : mn;
            float ps = 0.f;
#pragma unroll
            for (int jt = 0; jt < 4; ++jt) {
                ushort pb = f2bf(__expf(s[jt][r] - safe));
                Pw[quad * 4 + r][jt * 16 + l15] = pb;
                ps += bf2f(pb);
            }
            ps += __shfl_xor(ps, 1);
            ps += __shfl_xor(ps, 2);
            ps += __shfl_xor(ps, 4);
            ps += __shfl_xor(ps, 8);
            m_run[r] = mn;
            l_run[r] = l_run[r] * alpha + ps;
            al[r] = alpha;
        }

#pragma unroll
        for (int ct = 0; ct < 16; ++ct)
#pragma unroll
            for (int r = 0; r < 4; ++r) acc[ct][r] *= al[r];

        // PV: packed V fragment loads (contiguous 1KB per (kk,ct))
        const ushort* vb = Vt + ((size_t)((bL + k0) >> 6) * 32) * 512 + lqoff;
#pragma unroll
        for (int kk = 0; kk < 2; ++kk) {
            bf16x8 pa = *(const bf16x8*)&Pw[l15][kk * 32 + quad * 8];
#pragma unroll
            for (int ct = 0; ct < 16; ++ct) {
                bf16x8 bv = *(const bf16x8*)(vb + (kk * 16 + ct) * 512);
                acc[ct] = __builtin_amdgcn_mfma_f32_16x16x32_bf16(pa, bv, acc[ct], 0, 0, 0);
            }
        }
    }

    float inv[4];
#pragma unroll
    for (int r = 0; r < 4; ++r)
        inv[r] = (l_run[r] > 0.f) ? (1.f / l_run[r]) : 0.f;
#pragma unroll
    for (int r = 0; r < 4; ++r) {
        float* orow = O + (bL + q0 + quad * 4 + r) * (size_t)D + l15;
#pragma unroll
        for (int ct = 0; ct < 16; ++ct)
            orow[ct * 16] = acc[ct][r] * inv[r];
    }
}

extern "C" void kernel_launch(void* const* d_in, const int* in_sizes, int n_in,
                              void* d_out, int out_size, void* d_ws, size_t ws_size,
                              hipStream_t stream) {
    const float* queries  = (const float*)d_in[0];
    const float* keys     = (const float*)d_in[1];
    const float* values_1 = (const float*)d_in[2];
    const void*  v1_mask  = d_in[3];
    const float* values_2 = (const float*)d_in[4];
    const void*  v2_mask  = d_in[5];
    const float* Wq       = (const float*)d_in[6];
    const float* Wk       = (const float*)d_in[7];
    const float* scaling  = (const float*)d_in[8];
    float* out = (float*)d_out;

    ushort* pq_hi = (ushort*)d_ws;
    ushort* pq_lo = pq_hi + (size_t)B * L * H;
    ushort* pk_hi = pq_lo + (size_t)B * L * H;
    ushort* pk_lo = pk_hi + (size_t)B * L * H;
    ushort* vt1   = pk_lo + (size_t)B * L * H;
    ushort* vt2   = vt1 + (size_t)B * L * D;
    float* fb1 = (float*)(vt2 + (size_t)B * L * D);
    float* fb2 = fb1 + B * L;

    mask_bias_kernel<<<2, 256, 0, stream>>>(v1_mask, v2_mask, fb1, fb2);
    proj_kernel<<<dim3(B * L / 16, 2, 2), 256, 0, stream>>>(
        queries, keys, Wq, Wk, scaling, pq_hi, pq_lo, pk_hi, pk_lo);
    vtrans_kernel<<<dim3(L / 64, D / 64, B * 2), 256, 0, stream>>>(
        values_1, values_2, vt1, vt2);
    flash_mfma_kernel<<<dim3(L / 64, B, 2), 256, 0, stream>>>(
        pq_hi, pq_lo, pk_hi, pk_lo, fb1, fb2, vt1, vt2, out);
}

// Round 5
// 376.941 us; speedup vs baseline: 7.6955x; 1.9836x over previous
//
#include <hip/hip_runtime.h>
#include <cstdint>
#include <math.h>

#define B 8
#define L 2048
#define D 256
#define H 128

typedef __attribute__((ext_vector_type(8))) _Float16 half8;
typedef __attribute__((ext_vector_type(4))) float f32x4;
typedef unsigned short ushort;
typedef unsigned int uint;

// Packed fragment layouts (reader order: lane l of the consuming wave reads
// bytes [l*16, l*16+16) of each 1KB block; lane l = quad*16 + l15):
//  Q/K arrays (B*L*H fp16):  block = (grow/16)*4 + h/32   (grow = b*L + row)
//     elem-in-block = ((h>>3)&3)*128 + (grow&15)*8 + (h&7)
//  V arrays (B*L*D fp16):   block = ((b*L+key)/32)*16 + d/16
//     elem-in-block = ((key&31)>>3)*128 + (d&15)*8 + (key&7)

// ---------------------------------------------------------------------------
// Masks -> float bias (0 keep, -inf masked). Layout (byte vs int32) detected
// from the first 256 words (present in both layouts; random bytes make some
// word >1 with probability ~1).
// ---------------------------------------------------------------------------
__global__ void mask_bias_kernel(const void* __restrict__ raw0,
                                 const void* __restrict__ raw1,
                                 float* __restrict__ out0,
                                 float* __restrict__ out1) {
    const void* raw = (blockIdx.y == 0) ? raw0 : raw1;
    float* out = (blockIdx.y == 0) ? out0 : out1;
    const int base = blockIdx.x * 1024;
    const int t = threadIdx.x;
    __shared__ int flag;
    if (t == 0) flag = 0;
    __syncthreads();
    const uint* wd = (const uint*)raw;
    if (wd[t] > 1u) flag = 1;
    __syncthreads();
    if (flag) {  // byte-bool layout
        const uint8_t* by = (const uint8_t*)raw;
#pragma unroll
        for (int j = 0; j < 4; ++j) {
            int i = base + t + 256 * j;
            out[i] = by[i] ? -INFINITY : 0.f;
        }
    } else {     // int32 layout
#pragma unroll
        for (int j = 0; j < 4; ++j) {
            int i = base + t + 256 * j;
            out[i] = wd[i] ? -INFINITY : 0.f;
        }
    }
}

// ---------------------------------------------------------------------------
// Projections -> fp16 packed: pq = relu(q@Wq^T), pk = relu(k@Wk^T)*scaling.
// W half (64 h x 256 d fp32) in LDS (XOR swizzle); input rows wave-broadcast.
// grid = (B*L/16, 2 h-halves, 2 tensors), block 256.
// ---------------------------------------------------------------------------
__launch_bounds__(256, 2)
__global__ void proj_kernel(const float* __restrict__ queries,
                            const float* __restrict__ keys,
                            const float* __restrict__ Wq,
                            const float* __restrict__ Wk,
                            const float* __restrict__ scaling,
                            _Float16* __restrict__ pqo,
                            _Float16* __restrict__ pko) {
    const int t = threadIdx.x;
    const int z = blockIdx.z;
    const int h0 = blockIdx.y * 64;
    const float* in = z ? keys : queries;
    const float4* W4 = (const float4*)(z ? Wk : Wq);

    __shared__ float4 Wl[64 * 64];
#pragma unroll
    for (int j = 0; j < 16; ++j) {
        int idx = t + 256 * j;
        int h = idx >> 6, i = idx & 63;
        Wl[h * 64 + (i ^ h)] = W4[(size_t)(h0 + h) * 64 + i];
    }
    __syncthreads();

    const int hl = t & 63;
    const int h = h0 + hl;
    const int rg = t >> 6;
    const int r0 = blockIdx.x * 16 + rg * 4;
    const float4* a = (const float4*)in + (size_t)r0 * 64;

    float s0 = 0.f, s1 = 0.f, s2 = 0.f, s3 = 0.f;
#pragma unroll 8
    for (int i = 0; i < 64; ++i) {
        float4 wv = Wl[hl * 64 + (i ^ hl)];
        float4 x0 = a[i];
        float4 x1 = a[i + 64];
        float4 x2 = a[i + 128];
        float4 x3 = a[i + 192];
        s0 += x0.x * wv.x + x0.y * wv.y + x0.z * wv.z + x0.w * wv.w;
        s1 += x1.x * wv.x + x1.y * wv.y + x1.z * wv.z + x1.w * wv.w;
        s2 += x2.x * wv.x + x2.y * wv.y + x2.z * wv.z + x2.w * wv.w;
        s3 += x3.x * wv.x + x3.y * wv.y + x3.z * wv.z + x3.w * wv.w;
    }
    s0 = fmaxf(s0, 0.f); s1 = fmaxf(s1, 0.f); s2 = fmaxf(s2, 0.f); s3 = fmaxf(s3, 0.f);
    if (z) {
        const float sc = scaling[h];
        s0 *= sc; s1 *= sc; s2 *= sc; s3 *= sc;
    }
    _Float16* o = z ? pko : pqo;
    const int hb = h >> 5, hq = (h >> 3) & 3, e = h & 7;
    float v[4] = {s0, s1, s2, s3};
#pragma unroll
    for (int r = 0; r < 4; ++r) {
        int rr = r0 + r;
        size_t off = (((size_t)(rr >> 4) * 4 + hb) << 9) + hq * 128 + (rr & 15) * 8 + e;
        o[off] = (_Float16)v[r];
    }
}

// ---------------------------------------------------------------------------
// V -> fp16 packed fragment layout, via LDS transpose.
// grid = (L/64, D/64, B*2); block tile = 64 keys x 64 d.
// ---------------------------------------------------------------------------
__global__ void vtrans_kernel(const float* __restrict__ v1,
                              const float* __restrict__ v2,
                              _Float16* __restrict__ vt1,
                              _Float16* __restrict__ vt2) {
    const int t = threadIdx.x;
    const int zz = blockIdx.z;
    const int b = zz & 7;
    const int which = zz >> 3;
    const float* src = (which ? v2 : v1) + (size_t)b * L * D;
    _Float16* dst = which ? vt2 : vt1;
    const int k0 = blockIdx.x * 64;
    const int d0 = blockIdx.y * 64;
    __shared__ float lt[64][65];   // lt[d][key]
#pragma unroll
    for (int p = 0; p < 4; ++p) {
        int kr = p * 16 + (t >> 4);
        float4 v = *(const float4*)(src + (size_t)(k0 + kr) * D + d0 + (t & 15) * 4);
        lt[(t & 15) * 4 + 0][kr] = v.x;
        lt[(t & 15) * 4 + 1][kr] = v.y;
        lt[(t & 15) * 4 + 2][kr] = v.z;
        lt[(t & 15) * 4 + 3][kr] = v.w;
    }
    __syncthreads();
    const int d = t & 63;
    const int kk = (t >> 6) & 1;
    const int qp = t >> 7;
    const size_t tile = ((size_t)b * L + k0) / 32 + kk;
    const int ct = (d0 + d) >> 4;
    _Float16* base = dst + (tile * 16 + ct) * 512 + (d & 15) * 8;
#pragma unroll
    for (int s = 0; s < 2; ++s) {
        const int qv = qp * 2 + s;
        const float* lr = &lt[d][kk * 32 + qv * 8];
        half8 hv;
#pragma unroll
        for (int e = 0; e < 8; ++e) hv[e] = (_Float16)lr[e];
        *(half8*)(base + qv * 128) = hv;
    }
}

// ---------------------------------------------------------------------------
// MFMA fp16 flash attention with async double-buffered LDS staging.
// Block = 64 q-rows (4 waves x 16), k-tiles of 32 keys, one barrier/iter.
// ---------------------------------------------------------------------------
__launch_bounds__(256, 2)
__global__ void flash_mfma_kernel(const _Float16* __restrict__ pq,
                                  const _Float16* __restrict__ pk,
                                  const float* __restrict__ fb1,
                                  const float* __restrict__ fb2,
                                  const _Float16* __restrict__ vt1,
                                  const _Float16* __restrict__ vt2,
                                  float* __restrict__ out) {
    const int t = threadIdx.x;
    const int w = t >> 6;
    const int lane = t & 63;
    const int l15 = lane & 15;
    const int quad = lane >> 4;
    const int bb = blockIdx.y;
    const int q0 = blockIdx.x * 64 + w * 16;

    const _Float16 *Qp, *Kp, *Vp;
    const float* fb;
    float* O;
    if (blockIdx.z == 0) { Qp = pq; Kp = pk; fb = fb1; Vp = vt1; O = out; }
    else                 { Qp = pk; Kp = pq; fb = fb2; Vp = vt2; O = out + (size_t)B * L * D; }

    // LDS: double-buffered tiles (blocks 0..7 = K(jt*4+hb), 8..23 = V(ct)),
    // per-wave P, bias row. 48 + 5 + 8 = 61 KB.
    __shared__ __attribute__((aligned(16))) _Float16 kv[2][24 * 512];
    __shared__ __attribute__((aligned(16))) _Float16 Pl[4][16][40];
    __shared__ float bias_l[L];

    const size_t bL = (size_t)bb * L;

    for (int i = t; i < L; i += 256) bias_l[i] = fb[bL + i];

    // Q A-frags in registers for the whole K-loop
    half8 aq[4];
    {
        const _Float16* qb = Qp + (size_t)((bL + q0) >> 4) * 2048 + lane * 8;
#pragma unroll
        for (int hb = 0; hb < 4; ++hb) aq[hb] = *(const half8*)(qb + hb * 512);
    }

    f32x4 acc[16];
#pragma unroll
    for (int ct = 0; ct < 16; ++ct) acc[ct] = (f32x4){0.f, 0.f, 0.f, 0.f};
    float m_run[4], l_run[4];
#pragma unroll
    for (int r = 0; r < 4; ++r) { m_run[r] = -INFINITY; l_run[r] = 0.f; }

    // async stage of k-tile `tile` into buffer `buf`: 24 x 1KB blocks, 6/wave
    auto stage = [&](int tile, int buf) {
        const size_t kk0 = bL + (size_t)tile * 32;
        _Float16* lb = kv[buf];
#pragma unroll
        for (int i = 0; i < 6; ++i) {
            const int c = w * 6 + i;
            const _Float16* g;
            if (c < 8)
                g = Kp + (size_t)(((kk0 >> 4) + (c >> 2)) * 4 + (c & 3)) * 512;
            else
                g = Vp + (size_t)((kk0 >> 5) * 16 + (c - 8)) * 512;
            __builtin_amdgcn_global_load_lds(
                (const __attribute__((address_space(1))) unsigned int*)(g + lane * 8),
                (__attribute__((address_space(3))) unsigned int*)(lb + c * 512),
                16, 0, 0);
        }
    };

    stage(0, 0);

    for (int it = 0; it < L / 32; ++it) {
        const int buf = it & 1;
        __syncthreads();                 // vmcnt(0): tile `it` landed; gates reuse
        if (it + 1 < L / 32) stage(it + 1, buf ^ 1);

        const _Float16* kb = kv[buf];
        const int k0 = it * 32;

        // QK^T: 2 key-tiles x 4 h-blocks
        f32x4 s[2];
#pragma unroll
        for (int jt = 0; jt < 2; ++jt) {
            f32x4 sv = (f32x4){0.f, 0.f, 0.f, 0.f};
#pragma unroll
            for (int hb = 0; hb < 4; ++hb) {
                half8 bk = *(const half8*)(kb + (jt * 4 + hb) * 512 + lane * 8);
                sv = __builtin_amdgcn_mfma_f32_16x16x32_f16(aq[hb], bk, sv, 0, 0, 0);
            }
            s[jt] = sv;
        }
        const float bias0 = bias_l[k0 + l15];
        const float bias1 = bias_l[k0 + 16 + l15];
#pragma unroll
        for (int r = 0; r < 4; ++r) { s[0][r] += bias0; s[1][r] += bias1; }

        // online softmax (row = quad*4+r over 16 lanes); P rounded to fp16
        // before the denominator sum so num/denom use identical weights.
        float al[4];
#pragma unroll
        for (int r = 0; r < 4; ++r) {
            float tm = fmaxf(s[0][r], s[1][r]);
            tm = fmaxf(tm, __shfl_xor(tm, 1));
            tm = fmaxf(tm, __shfl_xor(tm, 2));
            tm = fmaxf(tm, __shfl_xor(tm, 4));
            tm = fmaxf(tm, __shfl_xor(tm, 8));
            const float mn = fmaxf(m_run[r], tm);
            const float alpha = (m_run[r] == -INFINITY) ? 0.f : __expf(m_run[r] - mn);
            const float safe = (mn == -INFINITY) ? 0.f : mn;
            _Float16 p0 = (_Float16)__expf(s[0][r] - safe);
            _Float16 p1 = (_Float16)__expf(s[1][r] - safe);
            Pl[w][quad * 4 + r][l15] = p0;
            Pl[w][quad * 4 + r][16 + l15] = p1;
            float ps = (float)p0 + (float)p1;
            ps += __shfl_xor(ps, 1);
            ps += __shfl_xor(ps, 2);
            ps += __shfl_xor(ps, 4);
            ps += __shfl_xor(ps, 8);
            m_run[r] = mn;
            l_run[r] = l_run[r] * alpha + ps;
            al[r] = alpha;
        }

#pragma unroll
        for (int ct = 0; ct < 16; ++ct)
#pragma unroll
            for (int r = 0; r < 4; ++r) acc[ct][r] *= al[r];

        // PV: P(16x32) x V(32x256)
        half8 pa = *(const half8*)&Pl[w][l15][quad * 8];
#pragma unroll
        for (int ct = 0; ct < 16; ++ct) {
            half8 bv = *(const half8*)(kb + (8 + ct) * 512 + lane * 8);
            acc[ct] = __builtin_amdgcn_mfma_f32_16x16x32_f16(pa, bv, acc[ct], 0, 0, 0);
        }
    }

    float inv[4];
#pragma unroll
    for (int r = 0; r < 4; ++r)
        inv[r] = (l_run[r] > 0.f) ? (1.f / l_run[r]) : 0.f;
#pragma unroll
    for (int r = 0; r < 4; ++r) {
        float* orow = O + (bL + q0 + quad * 4 + r) * (size_t)D + l15;
#pragma unroll
        for (int ct = 0; ct < 16; ++ct)
            orow[ct * 16] = acc[ct][r] * inv[r];
    }
}

extern "C" void kernel_launch(void* const* d_in, const int* in_sizes, int n_in,
                              void* d_out, int out_size, void* d_ws, size_t ws_size,
                              hipStream_t stream) {
    const float* queries  = (const float*)d_in[0];
    const float* keys     = (const float*)d_in[1];
    const float* values_1 = (const float*)d_in[2];
    const void*  v1_mask  = d_in[3];
    const float* values_2 = (const float*)d_in[4];
    const void*  v2_mask  = d_in[5];
    const float* Wq       = (const float*)d_in[6];
    const float* Wk       = (const float*)d_in[7];
    const float* scaling  = (const float*)d_in[8];
    float* out = (float*)d_out;

    _Float16* pqw = (_Float16*)d_ws;                 // B*L*H fp16 (4 MB)
    _Float16* pkw = pqw + (size_t)B * L * H;         // 4 MB
    _Float16* vt1 = pkw + (size_t)B * L * H;         // B*L*D fp16 (8 MB)
    _Float16* vt2 = vt1 + (size_t)B * L * D;         // 8 MB
    float* fb1 = (float*)(vt2 + (size_t)B * L * D);  // 64 KB
    float* fb2 = fb1 + B * L;                        // 64 KB

    mask_bias_kernel<<<dim3(16, 2), 256, 0, stream>>>(v1_mask, v2_mask, fb1, fb2);
    proj_kernel<<<dim3(B * L / 16, 2, 2), 256, 0, stream>>>(
        queries, keys, Wq, Wk, scaling, pqw, pkw);
    vtrans_kernel<<<dim3(L / 64, D / 64, B * 2), 256, 0, stream>>>(
        values_1, values_2, vt1, vt2);
    flash_mfma_kernel<<<dim3(L / 64, B, 2), 256, 0, stream>>>(
        pqw, pkw, fb1, fb2, vt1, vt2, out);
}

// Round 6
// 256.050 us; speedup vs baseline: 11.3289x; 1.4721x over previous
//
#include <hip/hip_runtime.h>
#include <cstdint>
#include <math.h>

#define B 8
#define L 2048
#define D 256
#define H 128

typedef __attribute__((ext_vector_type(8))) _Float16 half8;
typedef __attribute__((ext_vector_type(4))) _Float16 half4t;
typedef __attribute__((ext_vector_type(4))) float f32x4;
typedef unsigned short ushort;
typedef unsigned int uint;

// Packed fragment layouts (reader: lane l = quad*16+l15 reads bytes
// [l*16, l*16+16) of each 1KB block):
//  Q/K (B*L*H fp16): block = (grow/16)*4 + h/32  (grow = b*L + row)
//     elem = ((h>>3)&3)*128 + (grow&15)*8 + (h&7)
//  V   (B*L*D fp16): block = ((b*L+key)/32)*16 + d/16
//     elem = ((key&31)>>3)*128 + (d&15)*8 + (key&7)
//  Wf  (2 x 128h x 256d fp16): block = (h/16)*8 + d/32
//     elem = ((d>>3)&3)*128 + (h&15)*8 + (d&7)

// ---------------------------------------------------------------------------
// prep: masks -> float bias (0 / -inf), W -> fp16 fragment blocks.
// grid (16, 2): y = tensor (mask0+Wq / mask1+Wk), 256 threads.
// ---------------------------------------------------------------------------
__global__ void prep_kernel(const void* __restrict__ raw0,
                            const void* __restrict__ raw1,
                            const float* __restrict__ Wq,
                            const float* __restrict__ Wk,
                            float* __restrict__ fb1,
                            float* __restrict__ fb2,
                            _Float16* __restrict__ Wf) {
    const int t = threadIdx.x;
    const int z = blockIdx.y;
    // --- mask chunk (1024 elems) ---
    {
        const void* raw = z ? raw1 : raw0;
        float* outb = z ? fb2 : fb1;
        const uint* wd = (const uint*)raw;
        __shared__ int flag;
        if (t == 0) flag = 0;
        __syncthreads();
        if (wd[t] > 1u) flag = 1;   // byte-bool layout iff some word >1
        __syncthreads();
        const int base = blockIdx.x * 1024;
        if (flag) {
            const uint8_t* by = (const uint8_t*)raw;
#pragma unroll
            for (int j = 0; j < 4; ++j) {
                int i = base + t + 256 * j;
                outb[i] = by[i] ? -INFINITY : 0.f;
            }
        } else {
#pragma unroll
            for (int j = 0; j < 4; ++j) {
                int i = base + t + 256 * j;
                outb[i] = wd[i] ? -INFINITY : 0.f;
            }
        }
    }
    // --- W chunk (8 d-elems of one h-row) ---
    {
        const float* Wsrc = z ? Wk : Wq;
        const int chunk = blockIdx.x * 256 + t;   // 0..4095
        const int h = chunk >> 5;
        const int d0 = (chunk & 31) * 8;
        float4 v0 = *(const float4*)(Wsrc + (size_t)h * 256 + d0);
        float4 v1 = *(const float4*)(Wsrc + (size_t)h * 256 + d0 + 4);
        half8 hv;
        hv[0] = (_Float16)v0.x; hv[1] = (_Float16)v0.y;
        hv[2] = (_Float16)v0.z; hv[3] = (_Float16)v0.w;
        hv[4] = (_Float16)v1.x; hv[5] = (_Float16)v1.y;
        hv[6] = (_Float16)v1.z; hv[7] = (_Float16)v1.w;
        const int db = d0 >> 5, dq = (d0 >> 3) & 3;
        size_t off = (size_t)z * 32768 +
                     ((size_t)((h >> 4) * 8 + db)) * 512 + dq * 128 + (h & 15) * 8;
        *(half8*)(Wf + off) = hv;
    }
}

// ---------------------------------------------------------------------------
// MFMA projections: pq = relu(q@Wq^T), pk = relu(k@Wk^T)*scaling, fp16 packed.
// Block: 64 rows x 64 h (one h-half), K=256. grid (B*L/64, 2, 2), 256 thr.
// W staged via global_load_lds from Wf; A staged fp32->fp16 via VGPRs.
// ---------------------------------------------------------------------------
__launch_bounds__(256, 2)
__global__ void proj_mfma_kernel(const float* __restrict__ queries,
                                 const float* __restrict__ keys,
                                 const _Float16* __restrict__ Wf,
                                 const float* __restrict__ scaling,
                                 _Float16* __restrict__ pqo,
                                 _Float16* __restrict__ pko) {
    const int t = threadIdx.x;
    const int w = t >> 6;
    const int lane = t & 63;
    const int l15 = lane & 15;
    const int quad = lane >> 4;
    const int z = blockIdx.z;
    const int half = blockIdx.y;
    const int r0 = blockIdx.x * 64;        // global row over B*L
    const float* in = z ? keys : queries;
    _Float16* outp = z ? pko : pqo;

    __shared__ __attribute__((aligned(16))) _Float16 Wl[32 * 512];  // 32 KB
    __shared__ __attribute__((aligned(16))) _Float16 Af[4][8 * 512]; // 32 KB

    // stage W-half fragments (32 contiguous 1KB blocks)
    {
        const _Float16* wsrc = Wf + ((size_t)z * 64 + half * 32) * 512;
#pragma unroll
        for (int i = 0; i < 8; ++i) {
            const int f = w * 8 + i;
            __builtin_amdgcn_global_load_lds(
                (const __attribute__((address_space(1))) uint*)(wsrc + f * 512 + lane * 8),
                (__attribute__((address_space(3))) uint*)(Wl + f * 512 + lane * 8),
                16, 0, 0);
        }
    }
    // stage A: 64 rows x 256 fp32 -> fp16 fragment layout
    {
#pragma unroll
        for (int j = 0; j < 16; ++j) {
            const int idx = t + 256 * j;       // 0..4095 float4-chunks
            const int row = idx >> 6;          // 0..63 (wave-uniform)
            const int c4 = idx & 63;
            float4 v = *(const float4*)(in + ((size_t)(r0 + row)) * 256 + c4 * 4);
            half4t h4;
            h4[0] = (_Float16)v.x; h4[1] = (_Float16)v.y;
            h4[2] = (_Float16)v.z; h4[3] = (_Float16)v.w;
            const int rt = row >> 4, rl = row & 15;
            const int d0 = c4 * 4;
            const int db = d0 >> 5, dq = (d0 >> 3) & 3, e = d0 & 7;  // e in {0,4}
            *(half4t*)(&Af[rt][db * 512 + dq * 128 + rl * 8 + e]) = h4;
        }
    }
    __syncthreads();

    // A-frags for this wave (row tile rt = w)
    half8 a[8];
#pragma unroll
    for (int db = 0; db < 8; ++db)
        a[db] = *(const half8*)(&Af[w][db * 512 + lane * 8]);

    f32x4 acc[4];
#pragma unroll
    for (int hti = 0; hti < 4; ++hti) acc[hti] = (f32x4){0.f, 0.f, 0.f, 0.f};
#pragma unroll
    for (int db = 0; db < 8; ++db)
#pragma unroll
        for (int hti = 0; hti < 4; ++hti) {
            half8 bfrag = *(const half8*)(Wl + (hti * 8 + db) * 512 + lane * 8);
            acc[hti] = __builtin_amdgcn_mfma_f32_16x16x32_f16(a[db], bfrag, acc[hti], 0, 0, 0);
        }

    // epilogue: relu (+scaling), bounce through own A-region into packed layout
    _Float16* S = Af[w];   // wave-private now (a[] already in registers)
#pragma unroll
    for (int hti = 0; hti < 4; ++hti) {
        const int hl_ = hti * 16 + l15;        // h within the 64-h half
        const int hb = hl_ >> 5, hq = (hl_ >> 3) & 3, e = hl_ & 7;
        const float scl = z ? scaling[half * 64 + hl_] : 1.f;
#pragma unroll
        for (int r = 0; r < 4; ++r) {
            float v = fmaxf(acc[hti][r], 0.f) * scl;
            S[hb * 512 + hq * 128 + (quad * 4 + r) * 8 + e] = (_Float16)v;
        }
    }
    const size_t grow16 = (size_t)(r0 >> 4) + w;
    _Float16* gout = outp + (grow16 * 4 + half * 2) * 512;
#pragma unroll
    for (int hb = 0; hb < 2; ++hb) {
        half8 vv = *(const half8*)(S + hb * 512 + lane * 8);
        *(half8*)(gout + hb * 512 + lane * 8) = vv;
    }
}

// ---------------------------------------------------------------------------
// V -> fp16 packed fragment layout, via LDS transpose.
// grid = (L/64, D/64, B*2); block tile = 64 keys x 64 d.
// ---------------------------------------------------------------------------
__global__ void vtrans_kernel(const float* __restrict__ v1,
                              const float* __restrict__ v2,
                              _Float16* __restrict__ vt1,
                              _Float16* __restrict__ vt2) {
    const int t = threadIdx.x;
    const int zz = blockIdx.z;
    const int b = zz & 7;
    const int which = zz >> 3;
    const float* src = (which ? v2 : v1) + (size_t)b * L * D;
    _Float16* dst = which ? vt2 : vt1;
    const int k0 = blockIdx.x * 64;
    const int d0 = blockIdx.y * 64;
    __shared__ float lt[64][65];   // lt[d][key]
#pragma unroll
    for (int p = 0; p < 4; ++p) {
        int kr = p * 16 + (t >> 4);
        float4 v = *(const float4*)(src + (size_t)(k0 + kr) * D + d0 + (t & 15) * 4);
        lt[(t & 15) * 4 + 0][kr] = v.x;
        lt[(t & 15) * 4 + 1][kr] = v.y;
        lt[(t & 15) * 4 + 2][kr] = v.z;
        lt[(t & 15) * 4 + 3][kr] = v.w;
    }
    __syncthreads();
    const int d = t & 63;
    const int kk = (t >> 6) & 1;
    const int qp = t >> 7;
    const size_t tile = ((size_t)b * L + k0) / 32 + kk;
    const int ct = (d0 + d) >> 4;
    _Float16* base = dst + (tile * 16 + ct) * 512 + (d & 15) * 8;
#pragma unroll
    for (int s = 0; s < 2; ++s) {
        const int qv = qp * 2 + s;
        const float* lr = &lt[d][kk * 32 + qv * 8];
        half8 hv;
#pragma unroll
        for (int e = 0; e < 8; ++e) hv[e] = (_Float16)lr[e];
        *(half8*)(base + qv * 128) = hv;
    }
}

// ---------------------------------------------------------------------------
// MFMA fp16 flash attention; async double-buffered LDS staging; 3 blocks/CU.
// Block = 64 q-rows (4 waves x 16), k-tiles of 32 keys, one barrier/iter.
// ---------------------------------------------------------------------------
__launch_bounds__(256, 3)
__global__ void flash_mfma_kernel(const _Float16* __restrict__ pq,
                                  const _Float16* __restrict__ pk,
                                  const float* __restrict__ fb1,
                                  const float* __restrict__ fb2,
                                  const _Float16* __restrict__ vt1,
                                  const _Float16* __restrict__ vt2,
                                  float* __restrict__ out) {
    const int t = threadIdx.x;
    const int w = t >> 6;
    const int lane = t & 63;
    const int l15 = lane & 15;
    const int quad = lane >> 4;
    const int bb = blockIdx.y;
    const int q0 = blockIdx.x * 64 + w * 16;

    const _Float16 *Qp, *Kp, *Vp;
    const float* fb;
    float* O;
    if (blockIdx.z == 0) { Qp = pq; Kp = pk; fb = fb1; Vp = vt1; O = out; }
    else                 { Qp = pk; Kp = pq; fb = fb2; Vp = vt2; O = out + (size_t)B * L * D; }

    // LDS: double-buffered K(8)+V(16) 1KB blocks + per-wave P. 54.25 KB total.
    __shared__ __attribute__((aligned(16))) _Float16 kv[2][24 * 512];
    __shared__ __attribute__((aligned(16))) _Float16 Pl[4][16][40];

    const size_t bL = (size_t)bb * L;

    // Q A-frags in registers for the whole K-loop
    half8 aq[4];
    {
        const _Float16* qb = Qp + (size_t)((bL + q0) >> 4) * 2048 + lane * 8;
#pragma unroll
        for (int hb = 0; hb < 4; ++hb) aq[hb] = *(const half8*)(qb + hb * 512);
    }

    f32x4 acc[16];
#pragma unroll
    for (int ct = 0; ct < 16; ++ct) acc[ct] = (f32x4){0.f, 0.f, 0.f, 0.f};
    float m_run[4], l_run[4];
#pragma unroll
    for (int r = 0; r < 4; ++r) { m_run[r] = -INFINITY; l_run[r] = 0.f; }

    // async stage of k-tile `tile` into buffer `buf`: 24 x 1KB blocks, 6/wave
    auto stage = [&](int tile, int buf) {
        const size_t kk0 = bL + (size_t)tile * 32;
        _Float16* lb = kv[buf];
#pragma unroll
        for (int i = 0; i < 6; ++i) {
            const int c = w * 6 + i;
            const _Float16* g;
            if (c < 8)
                g = Kp + (size_t)(((kk0 >> 4) + (c >> 2)) * 4 + (c & 3)) * 512;
            else
                g = Vp + (size_t)((kk0 >> 5) * 16 + (c - 8)) * 512;
            __builtin_amdgcn_global_load_lds(
                (const __attribute__((address_space(1))) uint*)(g + lane * 8),
                (__attribute__((address_space(3))) uint*)(lb + c * 512),
                16, 0, 0);
        }
    };

    stage(0, 0);
    // register double-buffer of mask bias
    float nb0 = fb[bL + l15];
    float nb1 = fb[bL + 16 + l15];

    for (int it = 0; it < L / 32; ++it) {
        const int buf = it & 1;
        __syncthreads();               // vmcnt drain: tile `it` landed; gates reuse
        if (it + 1 < L / 32) stage(it + 1, buf ^ 1);
        const float bias0 = nb0, bias1 = nb1;
        if (it + 1 < L / 32) {
            nb0 = fb[bL + (it + 1) * 32 + l15];
            nb1 = fb[bL + (it + 1) * 32 + 16 + l15];
        }

        const _Float16* kb = kv[buf];

        // QK^T: 2 key-tiles x 4 h-blocks
        f32x4 s[2];
#pragma unroll
        for (int jt = 0; jt < 2; ++jt) {
            f32x4 sv = (f32x4){0.f, 0.f, 0.f, 0.f};
#pragma unroll
            for (int hb = 0; hb < 4; ++hb) {
                half8 bk = *(const half8*)(kb + (jt * 4 + hb) * 512 + lane * 8);
                sv = __builtin_amdgcn_mfma_f32_16x16x32_f16(aq[hb], bk, sv, 0, 0, 0);
            }
            s[jt] = sv;
        }
#pragma unroll
        for (int r = 0; r < 4; ++r) { s[0][r] += bias0; s[1][r] += bias1; }

        // online softmax (row = quad*4+r over 16 lanes); P rounded to fp16
        // before the denominator sum so num/denom use identical weights.
        float al[4];
#pragma unroll
        for (int r = 0; r < 4; ++r) {
            float tm = fmaxf(s[0][r], s[1][r]);
            tm = fmaxf(tm, __shfl_xor(tm, 1));
            tm = fmaxf(tm, __shfl_xor(tm, 2));
            tm = fmaxf(tm, __shfl_xor(tm, 4));
            tm = fmaxf(tm, __shfl_xor(tm, 8));
            const float mn = fmaxf(m_run[r], tm);
            const float alpha = (m_run[r] == -INFINITY) ? 0.f : __expf(m_run[r] - mn);
            const float safe = (mn == -INFINITY) ? 0.f : mn;
            _Float16 p0 = (_Float16)__expf(s[0][r] - safe);
            _Float16 p1 = (_Float16)__expf(s[1][r] - safe);
            Pl[w][quad * 4 + r][l15] = p0;
            Pl[w][quad * 4 + r][16 + l15] = p1;
            float ps = (float)p0 + (float)p1;
            ps += __shfl_xor(ps, 1);
            ps += __shfl_xor(ps, 2);
            ps += __shfl_xor(ps, 4);
            ps += __shfl_xor(ps, 8);
            m_run[r] = mn;
            l_run[r] = l_run[r] * alpha + ps;
            al[r] = alpha;
        }

        // rescale accumulator only when some row's max updated (alpha != 1)
        const bool need = (al[0] != 1.f) | (al[1] != 1.f) | (al[2] != 1.f) | (al[3] != 1.f);
        if (__any(need)) {
#pragma unroll
            for (int ct = 0; ct < 16; ++ct)
#pragma unroll
                for (int r = 0; r < 4; ++r) acc[ct][r] *= al[r];
        }

        // PV: P(16x32) x V(32x256)
        half8 pa = *(const half8*)&Pl[w][l15][quad * 8];
#pragma unroll
        for (int ct = 0; ct < 16; ++ct) {
            half8 bv = *(const half8*)(kb + (8 + ct) * 512 + lane * 8);
            acc[ct] = __builtin_amdgcn_mfma_f32_16x16x32_f16(pa, bv, acc[ct], 0, 0, 0);
        }
    }

    float inv[4];
#pragma unroll
    for (int r = 0; r < 4; ++r)
        inv[r] = (l_run[r] > 0.f) ? (1.f / l_run[r]) : 0.f;
#pragma unroll
    for (int r = 0; r < 4; ++r) {
        float* orow = O + (bL + q0 + quad * 4 + r) * (size_t)D + l15;
#pragma unroll
        for (int ct = 0; ct < 16; ++ct)
            orow[ct * 16] = acc[ct][r] * inv[r];
    }
}

extern "C" void kernel_launch(void* const* d_in, const int* in_sizes, int n_in,
                              void* d_out, int out_size, void* d_ws, size_t ws_size,
                              hipStream_t stream) {
    const float* queries  = (const float*)d_in[0];
    const float* keys     = (const float*)d_in[1];
    const float* values_1 = (const float*)d_in[2];
    const void*  v1_mask  = d_in[3];
    const float* values_2 = (const float*)d_in[4];
    const void*  v2_mask  = d_in[5];
    const float* Wq       = (const float*)d_in[6];
    const float* Wk       = (const float*)d_in[7];
    const float* scaling  = (const float*)d_in[8];
    float* out = (float*)d_out;

    _Float16* pqw = (_Float16*)d_ws;                 // B*L*H fp16 (4 MB)
    _Float16* pkw = pqw + (size_t)B * L * H;         // 4 MB
    _Float16* vt1 = pkw + (size_t)B * L * H;         // B*L*D fp16 (8 MB)
    _Float16* vt2 = vt1 + (size_t)B * L * D;         // 8 MB
    float* fb1 = (float*)(vt2 + (size_t)B * L * D);  // 64 KB
    float* fb2 = fb1 + B * L;                        // 64 KB
    _Float16* Wf = (_Float16*)(fb2 + B * L);         // 2*32768 fp16 (128 KB)

    prep_kernel<<<dim3(16, 2), 256, 0, stream>>>(
        v1_mask, v2_mask, Wq, Wk, fb1, fb2, Wf);
    proj_mfma_kernel<<<dim3(B * L / 64, 2, 2), 256, 0, stream>>>(
        queries, keys, Wf, scaling, pqw, pkw);
    vtrans_kernel<<<dim3(L / 64, D / 64, B * 2), 256, 0, stream>>>(
        values_1, values_2, vt1, vt2);
    flash_mfma_kernel<<<dim3(L / 64, B, 2), 256, 0, stream>>>(
        pqw, pkw, fb1, fb2, vt1, vt2, out);
}

// Round 7
// 242.984 us; speedup vs baseline: 11.9380x; 1.0538x over previous
//
#include <hip/hip_runtime.h>
#include <cstdint>
#include <math.h>

#define B 8
#define L 2048
#define D 256
#define H 128

typedef __attribute__((ext_vector_type(8))) _Float16 half8;
typedef __attribute__((ext_vector_type(4))) _Float16 half4t;
typedef __attribute__((ext_vector_type(4))) float f32x4;
typedef unsigned short ushort;
typedef unsigned int uint;

// Layouts:
//  pq/pk (B*L*H fp16) packed MFMA-frag blocks: block=(grow/16)*4+h/32,
//     elem=((h>>3)&3)*128+(grow&15)*8+(h&7)   [proven R4-R6]
//  vt (B*L*D fp16): block=((b*L+key)/32)*16+d/16, elem=((key&31)>>3)*128+(d&15)*8+(key&7)
//  S  (fp16): S[b][qt16][kt16][q16*16+k16], microtile-max-shifted (values <= 0)
//  tmax1[b][q][kt64=32] = max_k(s+bias1) per 64-key tile (f32)
//  tmax2[b][k][qt16=128] = max_q(s+bias2) per 16-q tile (f32)
//  mmax[b][qt16][kt16] = raw microtile max (f32)

// ---------------------------------------------------------------------------
// prep: masks -> float bias (0 / -inf), W -> fp16 fragment blocks.
// ---------------------------------------------------------------------------
__global__ void prep_kernel(const void* __restrict__ raw0,
                            const void* __restrict__ raw1,
                            const float* __restrict__ Wq,
                            const float* __restrict__ Wk,
                            float* __restrict__ fb1,
                            float* __restrict__ fb2,
                            _Float16* __restrict__ Wf) {
    const int t = threadIdx.x;
    const int z = blockIdx.y;
    {
        const void* raw = z ? raw1 : raw0;
        float* outb = z ? fb2 : fb1;
        const uint* wd = (const uint*)raw;
        __shared__ int flag;
        if (t == 0) flag = 0;
        __syncthreads();
        if (wd[t] > 1u) flag = 1;   // byte-bool layout iff some word >1
        __syncthreads();
        const int base = blockIdx.x * 1024;
        if (flag) {
            const uint8_t* by = (const uint8_t*)raw;
#pragma unroll
            for (int j = 0; j < 4; ++j) {
                int i = base + t + 256 * j;
                outb[i] = by[i] ? -INFINITY : 0.f;
            }
        } else {
#pragma unroll
            for (int j = 0; j < 4; ++j) {
                int i = base + t + 256 * j;
                outb[i] = wd[i] ? -INFINITY : 0.f;
            }
        }
    }
    {
        const float* Wsrc = z ? Wk : Wq;
        const int chunk = blockIdx.x * 256 + t;   // 0..4095
        const int h = chunk >> 5;
        const int d0 = (chunk & 31) * 8;
        float4 v0 = *(const float4*)(Wsrc + (size_t)h * 256 + d0);
        float4 v1 = *(const float4*)(Wsrc + (size_t)h * 256 + d0 + 4);
        half8 hv;
        hv[0] = (_Float16)v0.x; hv[1] = (_Float16)v0.y;
        hv[2] = (_Float16)v0.z; hv[3] = (_Float16)v0.w;
        hv[4] = (_Float16)v1.x; hv[5] = (_Float16)v1.y;
        hv[6] = (_Float16)v1.z; hv[7] = (_Float16)v1.w;
        const int db = d0 >> 5, dq = (d0 >> 3) & 3;
        size_t off = (size_t)z * 32768 +
                     ((size_t)((h >> 4) * 8 + db)) * 512 + dq * 128 + (h & 15) * 8;
        *(half8*)(Wf + off) = hv;
    }
}

// ---------------------------------------------------------------------------
// MFMA projections (unchanged from R6): pq/pk fp16 packed.
// ---------------------------------------------------------------------------
__launch_bounds__(256, 2)
__global__ void proj_mfma_kernel(const float* __restrict__ queries,
                                 const float* __restrict__ keys,
                                 const _Float16* __restrict__ Wf,
                                 const float* __restrict__ scaling,
                                 _Float16* __restrict__ pqo,
                                 _Float16* __restrict__ pko) {
    const int t = threadIdx.x;
    const int w = t >> 6;
    const int lane = t & 63;
    const int l15 = lane & 15;
    const int quad = lane >> 4;
    const int z = blockIdx.z;
    const int half = blockIdx.y;
    const int r0 = blockIdx.x * 64;
    const float* in = z ? keys : queries;
    _Float16* outp = z ? pko : pqo;

    __shared__ __attribute__((aligned(16))) _Float16 Wl[32 * 512];
    __shared__ __attribute__((aligned(16))) _Float16 Af[4][8 * 512];

    {
        const _Float16* wsrc = Wf + ((size_t)z * 64 + half * 32) * 512;
#pragma unroll
        for (int i = 0; i < 8; ++i) {
            const int f = w * 8 + i;
            __builtin_amdgcn_global_load_lds(
                (const __attribute__((address_space(1))) uint*)(wsrc + f * 512 + lane * 8),
                (__attribute__((address_space(3))) uint*)(Wl + f * 512 + lane * 8),
                16, 0, 0);
        }
    }
    {
#pragma unroll
        for (int j = 0; j < 16; ++j) {
            const int idx = t + 256 * j;
            const int row = idx >> 6;
            const int c4 = idx & 63;
            float4 v = *(const float4*)(in + ((size_t)(r0 + row)) * 256 + c4 * 4);
            half4t h4;
            h4[0] = (_Float16)v.x; h4[1] = (_Float16)v.y;
            h4[2] = (_Float16)v.z; h4[3] = (_Float16)v.w;
            const int rt = row >> 4, rl = row & 15;
            const int d0 = c4 * 4;
            const int db = d0 >> 5, dq = (d0 >> 3) & 3, e = d0 & 7;
            *(half4t*)(&Af[rt][db * 512 + dq * 128 + rl * 8 + e]) = h4;
        }
    }
    __syncthreads();

    half8 a[8];
#pragma unroll
    for (int db = 0; db < 8; ++db)
        a[db] = *(const half8*)(&Af[w][db * 512 + lane * 8]);

    f32x4 acc[4];
#pragma unroll
    for (int hti = 0; hti < 4; ++hti) acc[hti] = (f32x4){0.f, 0.f, 0.f, 0.f};
#pragma unroll
    for (int db = 0; db < 8; ++db)
#pragma unroll
        for (int hti = 0; hti < 4; ++hti) {
            half8 bfrag = *(const half8*)(Wl + (hti * 8 + db) * 512 + lane * 8);
            acc[hti] = __builtin_amdgcn_mfma_f32_16x16x32_f16(a[db], bfrag, acc[hti], 0, 0, 0);
        }

    _Float16* S = Af[w];
#pragma unroll
    for (int hti = 0; hti < 4; ++hti) {
        const int hl_ = hti * 16 + l15;
        const int hb = hl_ >> 5, hq = (hl_ >> 3) & 3, e = hl_ & 7;
        const float scl = z ? scaling[half * 64 + hl_] : 1.f;
#pragma unroll
        for (int r = 0; r < 4; ++r) {
            float v = fmaxf(acc[hti][r], 0.f) * scl;
            S[hb * 512 + hq * 128 + (quad * 4 + r) * 8 + e] = (_Float16)v;
        }
    }
    const size_t grow16 = (size_t)(r0 >> 4) + w;
    _Float16* gout = outp + (grow16 * 4 + half * 2) * 512;
#pragma unroll
    for (int hb = 0; hb < 2; ++hb) {
        half8 vv = *(const half8*)(S + hb * 512 + lane * 8);
        *(half8*)(gout + hb * 512 + lane * 8) = vv;
    }
}

// ---------------------------------------------------------------------------
// V -> fp16 packed fragment layout (unchanged from R6).
// ---------------------------------------------------------------------------
__global__ void vtrans_kernel(const float* __restrict__ v1,
                              const float* __restrict__ v2,
                              _Float16* __restrict__ vt1,
                              _Float16* __restrict__ vt2) {
    const int t = threadIdx.x;
    const int zz = blockIdx.z;
    const int b = zz & 7;
    const int which = zz >> 3;
    const float* src = (which ? v2 : v1) + (size_t)b * L * D;
    _Float16* dst = which ? vt2 : vt1;
    const int k0 = blockIdx.x * 64;
    const int d0 = blockIdx.y * 64;
    __shared__ float lt[64][65];
#pragma unroll
    for (int p = 0; p < 4; ++p) {
        int kr = p * 16 + (t >> 4);
        float4 v = *(const float4*)(src + (size_t)(k0 + kr) * D + d0 + (t & 15) * 4);
        lt[(t & 15) * 4 + 0][kr] = v.x;
        lt[(t & 15) * 4 + 1][kr] = v.y;
        lt[(t & 15) * 4 + 2][kr] = v.z;
        lt[(t & 15) * 4 + 3][kr] = v.w;
    }
    __syncthreads();
    const int d = t & 63;
    const int kk = (t >> 6) & 1;
    const int qp = t >> 7;
    const size_t tile = ((size_t)b * L + k0) / 32 + kk;
    const int ct = (d0 + d) >> 4;
    _Float16* base = dst + (tile * 16 + ct) * 512 + (d & 15) * 8;
#pragma unroll
    for (int s = 0; s < 2; ++s) {
        const int qv = qp * 2 + s;
        const float* lr = &lt[d][kk * 32 + qv * 8];
        half8 hv;
#pragma unroll
        for (int e = 0; e < 8; ++e) hv[e] = (_Float16)lr[e];
        *(half8*)(base + qv * 128) = hv;
    }
}

// ---------------------------------------------------------------------------
// score: S = pq·pk^T computed ONCE; store fp16 microtiles shifted by microtile
// max; emit tmax1 (row max over k, bias1), tmax2 (col max over 16q, bias2),
// mmax (raw microtile max). No LDS; frags straight from L2/L3.
// grid (L/64 kt, L/64 qt, B), block 256.
// ---------------------------------------------------------------------------
__launch_bounds__(256)
__global__ void score_kernel(const _Float16* __restrict__ pq,
                             const _Float16* __restrict__ pk,
                             const float* __restrict__ fb1,
                             const float* __restrict__ fb2,
                             _Float16* __restrict__ Sb,
                             float* __restrict__ tmax1,
                             float* __restrict__ tmax2,
                             float* __restrict__ mmax) {
    const int t = threadIdx.x;
    const int w = t >> 6;
    const int lane = t & 63;
    const int l15 = lane & 15;
    const int quad = lane >> 4;
    const int bb = blockIdx.z;
    const int k0 = blockIdx.x * 64;
    const int q0 = blockIdx.y * 64;
    const size_t bL = (size_t)bb * L;
    const int qt16 = (q0 >> 4) + w;

    half8 aq[4];
    {
        const _Float16* qb = pq + ((bL + q0 + w * 16) >> 4) * 2048 + lane * 8;
#pragma unroll
        for (int hb = 0; hb < 4; ++hb) aq[hb] = *(const half8*)(qb + hb * 512);
    }

    f32x4 s[4];
#pragma unroll
    for (int jt = 0; jt < 4; ++jt) {
        const _Float16* kb = pk + ((bL + k0 + jt * 16) >> 4) * 2048 + lane * 8;
        f32x4 sv = (f32x4){0.f, 0.f, 0.f, 0.f};
#pragma unroll
        for (int hb = 0; hb < 4; ++hb) {
            half8 bk = *(const half8*)(kb + hb * 512);
            sv = __builtin_amdgcn_mfma_f32_16x16x32_f16(aq[hb], bk, sv, 0, 0, 0);
        }
        s[jt] = sv;
    }

    float b1j[4];
#pragma unroll
    for (int jt = 0; jt < 4; ++jt) b1j[jt] = fb1[bL + k0 + jt * 16 + l15];
    float4 b2v = *(const float4*)(fb2 + bL + q0 + w * 16 + quad * 4);
    float b2r[4] = {b2v.x, b2v.y, b2v.z, b2v.w};

    // tmax1: per q-row max over the 64 keys (biased by fb1)
#pragma unroll
    for (int r = 0; r < 4; ++r) {
        float m1 = -INFINITY;
#pragma unroll
        for (int jt = 0; jt < 4; ++jt) m1 = fmaxf(m1, s[jt][r] + b1j[jt]);
        m1 = fmaxf(m1, __shfl_xor(m1, 1));
        m1 = fmaxf(m1, __shfl_xor(m1, 2));
        m1 = fmaxf(m1, __shfl_xor(m1, 4));
        m1 = fmaxf(m1, __shfl_xor(m1, 8));
        if (l15 == 0)
            tmax1[(bL + q0 + w * 16 + quad * 4 + r) * 32 + blockIdx.x] = m1;
    }

    // per 16x16 microtile: tmax2 (biased by fb2) + raw mmax + shifted store
#pragma unroll
    for (int jt = 0; jt < 4; ++jt) {
        float m2 = -INFINITY, mm = -INFINITY;
#pragma unroll
        for (int r = 0; r < 4; ++r) {
            m2 = fmaxf(m2, s[jt][r] + b2r[r]);
            mm = fmaxf(mm, s[jt][r]);
        }
        m2 = fmaxf(m2, __shfl_xor(m2, 16));
        m2 = fmaxf(m2, __shfl_xor(m2, 32));
        if (quad == 0)
            tmax2[(bL + k0 + jt * 16 + l15) * 128 + qt16] = m2;
        mm = fmaxf(mm, __shfl_xor(mm, 1));
        mm = fmaxf(mm, __shfl_xor(mm, 2));
        mm = fmaxf(mm, __shfl_xor(mm, 4));
        mm = fmaxf(mm, __shfl_xor(mm, 8));
        mm = fmaxf(mm, __shfl_xor(mm, 16));
        mm = fmaxf(mm, __shfl_xor(mm, 32));
        const size_t mti = ((size_t)bb * 128 + qt16) * 128 + (k0 >> 4) + jt;
        if (lane == 0) mmax[mti] = mm;
        _Float16* sp = Sb + mti * 256 + l15;
#pragma unroll
        for (int r = 0; r < 4; ++r)
            sp[(quad * 4 + r) * 16] = (_Float16)(s[jt][r] - mm);
    }
}

// ---------------------------------------------------------------------------
// attn_pv: both branches. Known row-maxes -> streaming exp + PV, no online
// softmax. z=0: rows=q, S direct global b128 reads. z=1: rows=key, S
// microtiles staged via global_load_lds + LDS transpose.
// Block = 64 out-rows (4 waves x 16), inner tiles of 32, grid (L/64, B, 2).
// ---------------------------------------------------------------------------
__launch_bounds__(256, 3)
__global__ void attn_pv_kernel(const _Float16* __restrict__ Sb,
                               const float* __restrict__ fb1,
                               const float* __restrict__ fb2,
                               const float* __restrict__ tmax1,
                               const float* __restrict__ tmax2,
                               const float* __restrict__ mmax,
                               const _Float16* __restrict__ vt1,
                               const _Float16* __restrict__ vt2,
                               float* __restrict__ out) {
    const int t = threadIdx.x;
    const int w = t >> 6;
    const int lane = t & 63;
    const int l15 = lane & 15;
    const int quad = lane >> 4;
    const int bb = blockIdx.y;
    const int z = blockIdx.z;
    const int r0 = blockIdx.x * 64;
    const size_t bL = (size_t)bb * L;

    const _Float16* Vp = z ? vt2 : vt1;
    const float* fbb = (z ? fb2 : fb1) + bL;
    float* O = out + (z ? (size_t)B * L * D : 0);

    __shared__ __attribute__((aligned(16))) _Float16 kv[2][16 * 512];
    __shared__ __attribute__((aligned(16))) _Float16 sst[2][4 * 1056];
    __shared__ float mred[64][4];

    // m_row partial reduce into LDS
    {
        const int row = t >> 2, part = t & 3;
        float mv = -INFINITY;
        if (z == 0) {
            const float4* p4 = (const float4*)(tmax1 + ((bL + r0 + row) << 5)) + part * 2;
#pragma unroll
            for (int i = 0; i < 2; ++i) {
                float4 v = p4[i];
                mv = fmaxf(mv, fmaxf(fmaxf(v.x, v.y), fmaxf(v.z, v.w)));
            }
        } else {
            const float4* p4 = (const float4*)(tmax2 + ((bL + r0 + row) << 7)) + part * 8;
#pragma unroll
            for (int i = 0; i < 8; ++i) {
                float4 v = p4[i];
                mv = fmaxf(mv, fmaxf(fmaxf(v.x, v.y), fmaxf(v.z, v.w)));
            }
        }
        mred[row][part] = mv;
    }

    auto stage = [&](int it, int buf) {
        const _Float16* vb = Vp + ((bL + it * 32) >> 5) * (size_t)(16 * 512);
#pragma unroll
        for (int i = 0; i < 4; ++i) {
            const int c = w * 4 + i;
            __builtin_amdgcn_global_load_lds(
                (const __attribute__((address_space(1))) uint*)(vb + c * 512 + lane * 8),
                (__attribute__((address_space(3))) uint*)(&kv[buf][c * 512] + lane * 8),
                16, 0, 0);
        }
        if (z) {
            const _Float16* ssrc = Sb +
                (((size_t)bb * 128 + it * 2 + (w >> 1)) * 128 + (r0 >> 4) + (w & 1) * 2) * 256;
            __builtin_amdgcn_global_load_lds(
                (const __attribute__((address_space(1))) uint*)(ssrc + lane * 8),
                (__attribute__((address_space(3))) uint*)(&sst[buf][w * 1056] + lane * 8),
                16, 0, 0);
        }
    };

    stage(0, 0);
    __syncthreads();   // drains staging of tile 0 AND makes mred visible

    float mreg;
    {
        const int row = w * 16 + l15;
        mreg = fmaxf(fmaxf(mred[row][0], mred[row][1]),
                     fmaxf(mred[row][2], mred[row][3]));
        mreg = fmaxf(mreg, -1e30f);   // guard vs all-masked (never hit in practice)
    }

    f32x4 acc[16];
#pragma unroll
    for (int ct = 0; ct < 16; ++ct) acc[ct] = (f32x4){0.f, 0.f, 0.f, 0.f};
    float lsum = 0.f;

    for (int it = 0; it < 64; ++it) {
        const int buf = it & 1;
        if (it) __syncthreads();           // tile `it` landed; prev bufs free
        if (it + 1 < 64) stage(it + 1, buf ^ 1);

        // microtile-max correction
        float c;
        {
            const size_t mmidx = z
                ? (((size_t)bb * 128 + it * 2 + (quad >> 1)) * 128 + (r0 >> 4) + w)
                : (((size_t)bb * 128 + (r0 >> 4) + w) * 128 + it * 2 + (quad >> 1));
            c = mmax[mmidx] - mreg;
        }
        // inner-axis mask bias (8 consecutive)
        float bj[8];
        {
            const float4* bp = (const float4*)(fbb + it * 32 + quad * 8);
            float4 b0 = bp[0], b1 = bp[1];
            bj[0] = b0.x; bj[1] = b0.y; bj[2] = b0.z; bj[3] = b0.w;
            bj[4] = b1.x; bj[5] = b1.y; bj[6] = b1.z; bj[7] = b1.w;
        }
        // scores
        float pj[8];
        if (z == 0) {
            const _Float16* sp = Sb +
                (((size_t)bb * 128 + (r0 >> 4) + w) * 128 + it * 2 + (quad >> 1)) * 256 +
                l15 * 16 + (quad & 1) * 8;
            half8 sv = *(const half8*)sp;
#pragma unroll
            for (int j = 0; j < 8; ++j) pj[j] = (float)sv[j];
        } else {
            const _Float16* sl = &sst[buf][((quad >> 1) * 2 + (w >> 1)) * 1056 +
                                           (w & 1) * 256 + l15];
#pragma unroll
            for (int j = 0; j < 8; ++j)
                pj[j] = (float)sl[((quad & 1) * 8 + j) * 16];
        }
        // P = exp(s' + c + bias), fp16-rounded for num/denom consistency
        half8 pa;
#pragma unroll
        for (int j = 0; j < 8; ++j) {
            float p = __expf(pj[j] + c + bj[j]);
            pa[j] = (_Float16)p;
            lsum += (float)pa[j];
        }
        // PV
        const _Float16* kb = kv[buf];
#pragma unroll
        for (int ct = 0; ct < 16; ++ct) {
            half8 bv = *(const half8*)(kb + ct * 512 + lane * 8);
            acc[ct] = __builtin_amdgcn_mfma_f32_16x16x32_f16(pa, bv, acc[ct], 0, 0, 0);
        }
    }

    // combine l across quads (lanes with same l15 hold same row)
    lsum += __shfl_xor(lsum, 16);
    lsum += __shfl_xor(lsum, 32);
    float inv = (lsum > 0.f) ? (1.f / lsum) : 0.f;

#pragma unroll
    for (int r = 0; r < 4; ++r) {
        const float invr = __shfl(inv, quad * 4 + r);
        float* orow = O + (bL + r0 + w * 16 + quad * 4 + r) * (size_t)D + l15;
#pragma unroll
        for (int ct = 0; ct < 16; ++ct)
            orow[ct * 16] = acc[ct][r] * invr;
    }
}

extern "C" void kernel_launch(void* const* d_in, const int* in_sizes, int n_in,
                              void* d_out, int out_size, void* d_ws, size_t ws_size,
                              hipStream_t stream) {
    const float* queries  = (const float*)d_in[0];
    const float* keys     = (const float*)d_in[1];
    const float* values_1 = (const float*)d_in[2];
    const void*  v1_mask  = d_in[3];
    const float* values_2 = (const float*)d_in[4];
    const void*  v2_mask  = d_in[5];
    const float* Wq       = (const float*)d_in[6];
    const float* Wk       = (const float*)d_in[7];
    const float* scaling  = (const float*)d_in[8];
    float* out = (float*)d_out;

    _Float16* pqw = (_Float16*)d_ws;                       // B*L*H   (4 MB)
    _Float16* pkw = pqw + (size_t)B * L * H;               // 4 MB
    _Float16* vt1 = pkw + (size_t)B * L * H;               // B*L*D   (8 MB)
    _Float16* vt2 = vt1 + (size_t)B * L * D;               // 8 MB
    _Float16* Sb  = vt2 + (size_t)B * L * D;               // B*128*128*256 (64 MB)
    float* fb1   = (float*)(Sb + (size_t)B * 128 * 128 * 256);  // 64 KB
    float* fb2   = fb1 + B * L;                            // 64 KB
    float* tmax1 = fb2 + B * L;                            // B*L*32   (2 MB)
    float* tmax2 = tmax1 + (size_t)B * L * 32;             // B*L*128  (8 MB)
    float* mmaxp = tmax2 + (size_t)B * L * 128;            // B*128*128 (512 KB)
    _Float16* Wf = (_Float16*)(mmaxp + (size_t)B * 128 * 128);  // 128 KB

    prep_kernel<<<dim3(16, 2), 256, 0, stream>>>(
        v1_mask, v2_mask, Wq, Wk, fb1, fb2, Wf);
    proj_mfma_kernel<<<dim3(B * L / 64, 2, 2), 256, 0, stream>>>(
        queries, keys, Wf, scaling, pqw, pkw);
    vtrans_kernel<<<dim3(L / 64, D / 64, B * 2), 256, 0, stream>>>(
        values_1, values_2, vt1, vt2);
    score_kernel<<<dim3(L / 64, L / 64, B), 256, 0, stream>>>(
        pqw, pkw, fb1, fb2, Sb, tmax1, tmax2, mmaxp);
    attn_pv_kernel<<<dim3(L / 64, B, 2), 256, 0, stream>>>(
        Sb, fb1, fb2, tmax1, tmax2, mmaxp, vt1, vt2, out);
}